// Round 5
// baseline (1384.013 us; speedup 1.0000x reference)
//
#include <hip/hip_runtime.h>
#include <hip/hip_bf16.h>

#define D 1024
#define NQ 8192
#define NM 32768
#define TOPK 32

typedef __attribute__((ext_vector_type(8))) __bf16 bf16x8;
typedef __attribute__((ext_vector_type(4))) float f32x4;

__device__ __forceinline__ void load_lds16(const void* g, void* l) {
  __builtin_amdgcn_global_load_lds(
      (const __attribute__((address_space(1))) void*)g,
      (__attribute__((address_space(3))) void*)l, 16, 0, 0);
}

__device__ __forceinline__ ushort f2bf(float f) {
  unsigned u = __float_as_uint(f);
  unsigned r = (u + 0x7FFFu + ((u >> 16) & 1u)) >> 16;
  return (ushort)r;
}

// ---------- row L2-normalize f32 -> bf16 ----------
__global__ __launch_bounds__(256) void norm_cast_k(const float* __restrict__ in,
                                                   ushort* __restrict__ out) {
  const int row = blockIdx.x;
  const int tid = threadIdx.x;
  const float4 v = ((const float4*)(in + (size_t)row * D))[tid];
  float ss = v.x * v.x + v.y * v.y + v.z * v.z + v.w * v.w;
#pragma unroll
  for (int off = 32; off; off >>= 1) ss += __shfl_xor(ss, off, 64);
  __shared__ float wsum[4];
  const int wid = tid >> 6, lane = tid & 63;
  if (lane == 0) wsum[wid] = ss;
  __syncthreads();
  const float tot = wsum[0] + wsum[1] + wsum[2] + wsum[3];
  const float inv = 1.0f / fmaxf(sqrtf(tot), 1e-12f);
  ushort4 o;
  o.x = f2bf(v.x * inv);
  o.y = f2bf(v.y * inv);
  o.z = f2bf(v.z * inv);
  o.w = f2bf(v.w * inv);
  ((ushort4*)(out + (size_t)row * D))[tid] = o;
}

// ---------- 256x256 bf16 GEMM, single-barrier pipelined schedule ----------
// BK=32, 4-slot LDS ring; frag reads prefetched one step ahead so ds_reads
// overlap MFMA clusters; only counted vmcnt; one s_barrier per K-tile.
#define SLOTU 8192  // ushorts per operand per ring slot (256x32)

#define STAGE_A(t, s)                            \
  do {                                           \
    load_lds16(gA0 + (t) * 32, lA0 + (s)*SLOTU); \
    load_lds16(gA1 + (t) * 32, lA1 + (s)*SLOTU); \
  } while (0)
#define STAGE_B(t, s)                            \
  do {                                           \
    load_lds16(gB0 + (t) * 32, lB0 + (s)*SLOTU); \
    load_lds16(gB1 + (t) * 32, lB1 + (s)*SLOTU); \
  } while (0)
#define AFRAG(s, mm) (*(const bf16x8*)&As[(s)*SLOTU + (a_r0 + (mm)*16) * 32 + kbx])
#define BFRAG(s, nn) (*(const bf16x8*)&Bs[(s)*SLOTU + (b_r0 + (nn)*16) * 32 + kbx])

__global__ __launch_bounds__(512, 2) void gemm256(const ushort* __restrict__ A,
                                                  const ushort* __restrict__ B,
                                                  ushort* __restrict__ C,
                                                  int nby) {
  __shared__ alignas(16) ushort As[4 * SLOTU];
  __shared__ alignas(16) ushort Bs[4 * SLOTU];
  const int tid = threadIdx.x;
  const int lane = tid & 63, wid = tid >> 6;

  // T1: bijective XCD swizzle on flat grid
  const int nwg = (int)gridDim.x;
  const int q = nwg >> 3, r = nwg & 7;
  const int xcd = (int)blockIdx.x & 7, pos = (int)blockIdx.x >> 3;
  const int wg = (xcd < r ? xcd * (q + 1) : r * (q + 1) + (xcd - r) * q) + pos;
  const int bx = wg / nby, by = wg % nby;

  const int wr = wid >> 2, wc = wid & 3;  // 2 x 4 waves; each owns 128x64 of C

  f32x4 acc[8][4];
#pragma unroll
  for (int m = 0; m < 8; m++)
#pragma unroll
    for (int n = 0; n < 4; n++) acc[m][n] = f32x4{0.f, 0.f, 0.f, 0.f};

  // staging addresses (global source pre-swizzled, LDS dest linear)
  const int j0 = wid * 2, j1 = wid * 2 + 1;
  const int srow = lane >> 2;
  const int skb = (lane & 3) ^ ((lane >> 3) & 3);
  const ushort* gA0 = A + ((size_t)by * 256 + 16 * j0 + srow) * D + skb * 8;
  const ushort* gA1 = A + ((size_t)by * 256 + 16 * j1 + srow) * D + skb * 8;
  const ushort* gB0 = B + ((size_t)bx * 256 + 16 * j0 + srow) * D + skb * 8;
  const ushort* gB1 = B + ((size_t)bx * 256 + 16 * j1 + srow) * D + skb * 8;
  ushort* const lA0 = As + j0 * 512;
  ushort* const lA1 = As + j1 * 512;
  ushort* const lB0 = Bs + j0 * 512;
  ushort* const lB1 = Bs + j1 * 512;

  // fragment read addressing (same swizzle on k-block)
  const int kbx = ((lane >> 4) ^ ((lane >> 1) & 3)) * 8;
  const int a_r0 = wr * 128 + (lane & 15);
  const int b_r0 = wc * 64 + (lane & 15);

  // prologue: stage tiles 0..2; certify t0,t1 (leave t2 in flight); prefetch frags(0)
  STAGE_A(0, 0);
  STAGE_B(0, 0);
  STAGE_A(1, 1);
  STAGE_B(1, 1);
  STAGE_A(2, 2);
  STAGE_B(2, 2);
  asm volatile("s_waitcnt vmcnt(4)" ::: "memory");
  __builtin_amdgcn_s_barrier();

  bf16x8 aA[2][4], bC[2][4];
#pragma unroll
  for (int m = 0; m < 4; ++m) {
    aA[0][m] = AFRAG(0, m);
    bC[0][m] = BFRAG(0, m);
  }

#pragma unroll 1
  for (int tb = 0; tb < 32; tb += 4) {
#pragma unroll
    for (int u = 0; u < 4; ++u) {
      const int t = tb + u;
      const int sc = u;              // t & 3 (tb multiple of 4)
      const int sn = (u + 1) & 3;    // (t+1) & 3
      const int pc = u & 1, pn = (u + 1) & 1;

      if (t < 29) STAGE_A(t + 3, (u + 3) & 3);

      // issue this tile's m=4..7 A-frag reads; they fly during cluster1
      bf16x8 aB0 = AFRAG(sc, 4), aB1 = AFRAG(sc, 5), aB2 = AFRAG(sc, 6), aB3 = AFRAG(sc, 7);

      __builtin_amdgcn_s_setprio(1);
#pragma unroll
      for (int m = 0; m < 4; ++m)
#pragma unroll
        for (int n = 0; n < 4; ++n)
          acc[m][n] = __builtin_amdgcn_mfma_f32_16x16x32_bf16(aA[pc][m], bC[pc][n], acc[m][n], 0, 0, 0);
      __builtin_amdgcn_s_setprio(0);

      if (t < 29) STAGE_B(t + 3, (u + 3) & 3);

      // prefetch next tile's frags; they fly during cluster2
      if (t < 31) {
#pragma unroll
        for (int m = 0; m < 4; ++m) {
          aA[pn][m] = AFRAG(sn, m);
          bC[pn][m] = BFRAG(sn, m);
        }
      }

      __builtin_amdgcn_s_setprio(1);
      acc[4][0] = __builtin_amdgcn_mfma_f32_16x16x32_bf16(aB0, bC[pc][0], acc[4][0], 0, 0, 0);
      acc[4][1] = __builtin_amdgcn_mfma_f32_16x16x32_bf16(aB0, bC[pc][1], acc[4][1], 0, 0, 0);
      acc[4][2] = __builtin_amdgcn_mfma_f32_16x16x32_bf16(aB0, bC[pc][2], acc[4][2], 0, 0, 0);
      acc[4][3] = __builtin_amdgcn_mfma_f32_16x16x32_bf16(aB0, bC[pc][3], acc[4][3], 0, 0, 0);
      acc[5][0] = __builtin_amdgcn_mfma_f32_16x16x32_bf16(aB1, bC[pc][0], acc[5][0], 0, 0, 0);
      acc[5][1] = __builtin_amdgcn_mfma_f32_16x16x32_bf16(aB1, bC[pc][1], acc[5][1], 0, 0, 0);
      acc[5][2] = __builtin_amdgcn_mfma_f32_16x16x32_bf16(aB1, bC[pc][2], acc[5][2], 0, 0, 0);
      acc[5][3] = __builtin_amdgcn_mfma_f32_16x16x32_bf16(aB1, bC[pc][3], acc[5][3], 0, 0, 0);
      acc[6][0] = __builtin_amdgcn_mfma_f32_16x16x32_bf16(aB2, bC[pc][0], acc[6][0], 0, 0, 0);
      acc[6][1] = __builtin_amdgcn_mfma_f32_16x16x32_bf16(aB2, bC[pc][1], acc[6][1], 0, 0, 0);
      acc[6][2] = __builtin_amdgcn_mfma_f32_16x16x32_bf16(aB2, bC[pc][2], acc[6][2], 0, 0, 0);
      acc[6][3] = __builtin_amdgcn_mfma_f32_16x16x32_bf16(aB2, bC[pc][3], acc[6][3], 0, 0, 0);
      acc[7][0] = __builtin_amdgcn_mfma_f32_16x16x32_bf16(aB3, bC[pc][0], acc[7][0], 0, 0, 0);
      acc[7][1] = __builtin_amdgcn_mfma_f32_16x16x32_bf16(aB3, bC[pc][1], acc[7][1], 0, 0, 0);
      acc[7][2] = __builtin_amdgcn_mfma_f32_16x16x32_bf16(aB3, bC[pc][2], acc[7][2], 0, 0, 0);
      acc[7][3] = __builtin_amdgcn_mfma_f32_16x16x32_bf16(aB3, bC[pc][3], acc[7][3], 0, 0, 0);
      __builtin_amdgcn_s_setprio(0);

      // certify slot t+2 for all waves before anyone reads it during t+1
      if (t < 29) asm volatile("s_waitcnt vmcnt(4)" ::: "memory");
      else if (t == 29) asm volatile("s_waitcnt vmcnt(0)" ::: "memory");
      __builtin_amdgcn_s_barrier();
    }
  }

  // C/D layout: row = (lane>>4)*4 + j, col = lane&15
  const size_t crow = (size_t)by * 256 + wr * 128 + ((lane >> 4) << 2);
  const size_t ccol = (size_t)bx * 256 + wc * 64 + (lane & 15);
#pragma unroll
  for (int m = 0; m < 8; m++)
#pragma unroll
    for (int n = 0; n < 4; n++)
#pragma unroll
      for (int j = 0; j < 4; j++)
        C[(crow + m * 16 + j) * (size_t)NM + ccol + n * 16] = f2bf(acc[m][n][j]);
}

// ---------- top-32: max -> near-max candidate filter -> 1-wave select ----------
#define CAP2 1024
__global__ __launch_bounds__(512) void topk_k(const ushort* __restrict__ scores, int row_base,
                                              const float* __restrict__ temp,
                                              float* __restrict__ attn,
                                              int* __restrict__ idx_out) {
  const int lrow = blockIdx.x;
  const int grow = row_base + lrow;
  const int tid = threadIdx.x;
  const int lane = tid & 63, wid = tid >> 6;
  __shared__ unsigned red[8];
  __shared__ int cnt_s;
  __shared__ unsigned ckey[CAP2];
  __shared__ unsigned cand64[64];
  __shared__ unsigned okey[TOPK];
  __shared__ int oidx[TOPK];

  const uint4* row4 = (const uint4*)(scores + (size_t)lrow * NM);
  unsigned kreg[32];
#pragma unroll
  for (int j = 0; j < 8; ++j) {
    const uint4 w = row4[tid + 512 * j];
    const unsigned wv[4] = {w.x, w.y, w.z, w.w};
#pragma unroll
    for (int p = 0; p < 4; ++p) {
      const unsigned u = wv[p];
      const unsigned m = (u >> 15) & 0x00010001u;
      kreg[j * 4 + p] = u ^ (m * 0x7FFFu + 0x80008000u);
    }
  }

  unsigned mhi = 0, mlo = 0;
#pragma unroll
  for (int r = 0; r < 32; ++r) {
    mhi = max(mhi, kreg[r] & 0xFFFF0000u);
    mlo = max(mlo, kreg[r] << 16);
  }
  unsigned tmax = max(mhi, mlo) >> 16;
#pragma unroll
  for (int off = 32; off; off >>= 1) tmax = max(tmax, __shfl_xor(tmax, off, 64));
  if (lane == 0) red[wid] = tmax;
  if (tid == 0) cnt_s = 0;
  __syncthreads();
  unsigned M = red[0];
#pragma unroll
  for (int w = 1; w < 8; ++w) M = max(M, red[w]);

  unsigned t0 = (M > 128) ? (M - 128) : 0u;
  int cnt = 0;
  for (int att = 0; att < 18; ++att) {
#pragma unroll
    for (int j = 0; j < 8; ++j) {
#pragma unroll
      for (int p = 0; p < 4; ++p) {
        const unsigned kk = kreg[j * 4 + p];
        const unsigned klo = kk & 0xFFFFu, khi = kk >> 16;
        const int base = (tid + 512 * j) * 8 + p * 2;
        if (klo >= t0) {
          const int q = atomicAdd(&cnt_s, 1);
          if (q < CAP2) ckey[q] = (klo << 16) | (unsigned)(32767 - base);
        }
        if (khi >= t0) {
          const int q = atomicAdd(&cnt_s, 1);
          if (q < CAP2) ckey[q] = (khi << 16) | (unsigned)(32767 - (base + 1));
        }
      }
    }
    __syncthreads();
    cnt = cnt_s;
    __syncthreads();
    if ((cnt >= TOPK && cnt <= CAP2) || att == 17) break;
    if (cnt < TOPK) t0 >>= 1;
    else t0 = t0 + ((M - t0 + 1) >> 1);
    if (tid == 0) cnt_s = 0;
    __syncthreads();
  }
  const int n = min(cnt, CAP2);

  if (tid < 64) {
    unsigned lo = t0, hi = M;
    while (lo < hi) {
      const unsigned mid = (lo + hi + 1) >> 1;
      int c = 0;
      for (int i = lane; i < n; i += 64) c += (int)((ckey[i] >> 16) >= mid);
#pragma unroll
      for (int off = 32; off; off >>= 1) c += __shfl_xor(c, off, 64);
      if (c >= TOPK) lo = mid; else hi = mid - 1;
    }
    const unsigned t32 = lo;
    int c32 = 0;
    for (int i = lane; i < n; i += 64) c32 += (int)((ckey[i] >> 16) >= t32);
#pragma unroll
    for (int off = 32; off; off >>= 1) c32 += __shfl_xor(c32, off, 64);

    if (c32 <= 64) {
      cand64[lane] = 0;
      int base = 0;
      for (int r0 = 0; r0 < n; r0 += 64) {
        const int i = r0 + lane;
        const unsigned k = (i < n) ? ckey[i] : 0u;
        const bool p = (k >> 16) >= t32;
        const unsigned long long bm = __ballot(p);
        if (p) {
          const int pos = base + __popcll(bm & ((1ull << lane) - 1ull));
          if (pos < 64) cand64[pos] = k;
        }
        base += __popcll(bm);
      }
      unsigned v = cand64[lane];
#pragma unroll
      for (int k2 = 2; k2 <= 64; k2 <<= 1) {
#pragma unroll
        for (int j = k2 >> 1; j > 0; j >>= 1) {
          const unsigned o = __shfl_xor(v, j, 64);
          const bool lower = (lane & j) == 0;
          const bool descB = (lane & k2) == 0;
          const unsigned mx = v > o ? v : o;
          const unsigned mn = v > o ? o : v;
          v = (lower == descB) ? mx : mn;
        }
      }
      if (lane < TOPK) {
        okey[lane] = v >> 16;
        oidx[lane] = 32767 - (int)(v & 0x7FFFu);
      }
    } else {
      for (int k = 0; k < TOPK; ++k) {
        unsigned bk = 0;
        for (int j = lane; j < n; j += 64) bk = max(bk, ckey[j]);
#pragma unroll
        for (int off = 32; off; off >>= 1) bk = max(bk, __shfl_xor(bk, off, 64));
        if (lane == 0) {
          okey[k] = bk >> 16;
          oidx[k] = 32767 - (int)(bk & 0x7FFFu);
        }
        for (int j = lane; j < n; j += 64)
          if (ckey[j] == bk) ckey[j] = 0;
      }
    }
  }
  __syncthreads();

  if (tid < TOPK) {
    const float T = fabsf(temp[0]);
    const unsigned k0 = okey[tid];
    const unsigned u0 = (k0 & 0x8000u) ? (k0 ^ 0x8000u) : (k0 ^ 0xFFFFu);
    const unsigned km = okey[0];
    const unsigned um = (km & 0x8000u) ? (km ^ 0x8000u) : (km ^ 0xFFFFu);
    const float s = __uint_as_float(u0 << 16) * T;
    const float mx = __uint_as_float(um << 16) * T;
    const float e = __expf(s - mx);
    float sum = e;
#pragma unroll
    for (int off = 16; off; off >>= 1) sum += __shfl_xor(sum, off, 32);
    attn[(size_t)grow * TOPK + tid] = e / sum;
    idx_out[(size_t)grow * TOPK + tid] = oidx[tid];
  }
}

// ---------- gather values + residual + LayerNorm ----------
__global__ __launch_bounds__(256) void gather_ln_k(const float* __restrict__ V,
                                                   const float* __restrict__ Q,
                                                   const float* __restrict__ gamma,
                                                   const float* __restrict__ beta,
                                                   const float* __restrict__ attn,
                                                   const int* __restrict__ idx,
                                                   float* __restrict__ out) {
  const int row = blockIdx.x, tid = threadIdx.x;
  __shared__ float a_s[TOPK];
  __shared__ int i_s[TOPK];
  __shared__ float redS[4], redQ[4];
  if (tid < TOPK) {
    a_s[tid] = attn[(size_t)row * TOPK + tid];
    i_s[tid] = idx[(size_t)row * TOPK + tid];
  }
  __syncthreads();
  float4 acc = {0.f, 0.f, 0.f, 0.f};
#pragma unroll
  for (int kb = 0; kb < TOPK; kb += 8) {
    float4 v[8];
#pragma unroll
    for (int u = 0; u < 8; ++u)
      v[u] = ((const float4*)(V + (size_t)i_s[kb + u] * D))[tid];
#pragma unroll
    for (int u = 0; u < 8; ++u) {
      const float a = a_s[kb + u];
      acc.x = fmaf(a, v[u].x, acc.x);
      acc.y = fmaf(a, v[u].y, acc.y);
      acc.z = fmaf(a, v[u].z, acc.z);
      acc.w = fmaf(a, v[u].w, acc.w);
    }
  }
  const float4 q = ((const float4*)(Q + (size_t)row * D))[tid];
  float4 x = {acc.x + q.x, acc.y + q.y, acc.z + q.z, acc.w + q.w};
  float s = x.x + x.y + x.z + x.w;
  float ss = x.x * x.x + x.y * x.y + x.z * x.z + x.w * x.w;
#pragma unroll
  for (int off = 32; off; off >>= 1) {
    s += __shfl_xor(s, off, 64);
    ss += __shfl_xor(ss, off, 64);
  }
  const int wid = tid >> 6, lane = tid & 63;
  if (lane == 0) { redS[wid] = s; redQ[wid] = ss; }
  __syncthreads();
  const float S = redS[0] + redS[1] + redS[2] + redS[3];
  const float SS = redQ[0] + redQ[1] + redQ[2] + redQ[3];
  const float mu = S * (1.0f / D);
  const float var = SS * (1.0f / D) - mu * mu;
  const float rstd = rsqrtf(var + 1e-5f);
  const float4 g = ((const float4*)gamma)[tid];
  const float4 b = ((const float4*)beta)[tid];
  float4 o;
  o.x = (x.x - mu) * rstd * g.x + b.x;
  o.y = (x.y - mu) * rstd * g.y + b.y;
  o.z = (x.z - mu) * rstd * g.z + b.z;
  o.w = (x.w - mu) * rstd * g.w + b.w;
  ((float4*)(out + (size_t)row * D))[tid] = o;
}

extern "C" void kernel_launch(void* const* d_in, const int* in_sizes, int n_in,
                              void* d_out, int out_size, void* d_ws, size_t ws_size,
                              hipStream_t stream) {
  const float* Q = (const float*)d_in[0];
  const float* K = (const float*)d_in[1];
  const float* V = (const float*)d_in[2];
  const float* T = (const float*)d_in[3];
  const float* G = (const float*)d_in[4];
  const float* Bt = (const float*)d_in[5];
  float* out = (float*)d_out;
  float* attn = out + (size_t)NQ * D;

  char* ws = (char*)d_ws;
  const size_t off_qn = 0;
  const size_t off_kn = off_qn + (size_t)NQ * D * 2;
  const size_t off_idx = off_kn + (size_t)NM * D * 2;
  const size_t off_sc = off_idx + (size_t)NQ * TOPK * sizeof(int);
  ushort* qn = (ushort*)(ws + off_qn);
  ushort* kn = (ushort*)(ws + off_kn);
  int* idx = (int*)(ws + off_idx);
  ushort* scores = (ushort*)(ws + off_sc);

  const size_t avail = ws_size > off_sc ? ws_size - off_sc : 0;
  int slice = 2048;
  while (slice > 256 && (size_t)slice * NM * 2ull > avail) slice >>= 1;

  norm_cast_k<<<NQ, 256, 0, stream>>>(Q, qn);
  norm_cast_k<<<NM, 256, 0, stream>>>(K, kn);

  const int nbx = NM / 256;
  for (int s0 = 0; s0 < NQ; s0 += slice) {
    const int nby = slice / 256;
    gemm256<<<nbx * nby, 512, 0, stream>>>(qn + (size_t)s0 * D, kn, scores, nby);
    topk_k<<<slice, 512, 0, stream>>>(scores, s0, T, attn, idx);
  }
  gather_ln_k<<<NQ, 256, 0, stream>>>(V, Q, G, Bt, attn, idx, out);
}

// Round 6
// 1382.139 us; speedup vs baseline: 1.0014x; 1.0014x over previous
//
#include <hip/hip_runtime.h>
#include <hip/hip_bf16.h>

#define D 1024
#define NQ 8192
#define NM 32768
#define TOPK 32

typedef __attribute__((ext_vector_type(8))) __bf16 bf16x8;
typedef __attribute__((ext_vector_type(4))) float f32x4;

__device__ __forceinline__ void load_lds16(const void* g, void* l) {
  __builtin_amdgcn_global_load_lds(
      (const __attribute__((address_space(1))) void*)g,
      (__attribute__((address_space(3))) void*)l, 16, 0, 0);
}

__device__ __forceinline__ ushort f2bf(float f) {
  unsigned u = __float_as_uint(f);
  unsigned r = (u + 0x7FFFu + ((u >> 16) & 1u)) >> 16;
  return (ushort)r;
}

// ---------- row L2-normalize f32 -> bf16 ----------
__global__ __launch_bounds__(256) void norm_cast_k(const float* __restrict__ in,
                                                   ushort* __restrict__ out) {
  const int row = blockIdx.x;
  const int tid = threadIdx.x;
  const float4 v = ((const float4*)(in + (size_t)row * D))[tid];
  float ss = v.x * v.x + v.y * v.y + v.z * v.z + v.w * v.w;
#pragma unroll
  for (int off = 32; off; off >>= 1) ss += __shfl_xor(ss, off, 64);
  __shared__ float wsum[4];
  const int wid = tid >> 6, lane = tid & 63;
  if (lane == 0) wsum[wid] = ss;
  __syncthreads();
  const float tot = wsum[0] + wsum[1] + wsum[2] + wsum[3];
  const float inv = 1.0f / fmaxf(sqrtf(tot), 1e-12f);
  ushort4 o;
  o.x = f2bf(v.x * inv);
  o.y = f2bf(v.y * inv);
  o.z = f2bf(v.z * inv);
  o.w = f2bf(v.w * inv);
  ((ushort4*)(out + (size_t)row * D))[tid] = o;
}

// ---------- 256x256 bf16 GEMM, single-barrier pipelined schedule ----------
// BK=32, 4-slot LDS ring; frag reads prefetched one step ahead so ds_reads
// overlap MFMA clusters; only counted vmcnt; one s_barrier per K-tile.
#define SLOTU 8192  // ushorts per operand per ring slot (256x32)

#define STAGE_A(t, s)                            \
  do {                                           \
    load_lds16(gA0 + (t) * 32, lA0 + (s)*SLOTU); \
    load_lds16(gA1 + (t) * 32, lA1 + (s)*SLOTU); \
  } while (0)
#define STAGE_B(t, s)                            \
  do {                                           \
    load_lds16(gB0 + (t) * 32, lB0 + (s)*SLOTU); \
    load_lds16(gB1 + (t) * 32, lB1 + (s)*SLOTU); \
  } while (0)
#define AFRAG(s, mm) (*(const bf16x8*)&As[(s)*SLOTU + (a_r0 + (mm)*16) * 32 + kbx])
#define BFRAG(s, nn) (*(const bf16x8*)&Bs[(s)*SLOTU + (b_r0 + (nn)*16) * 32 + kbx])

__global__ __launch_bounds__(512, 2) void gemm256(const ushort* __restrict__ A,
                                                  const ushort* __restrict__ B,
                                                  ushort* __restrict__ C,
                                                  int nby) {
  __shared__ alignas(16) ushort As[4 * SLOTU];
  __shared__ alignas(16) ushort Bs[4 * SLOTU];
  const int tid = threadIdx.x;
  const int lane = tid & 63, wid = tid >> 6;

  // T1: bijective XCD swizzle on flat grid
  const int nwg = (int)gridDim.x;
  const int q = nwg >> 3, r = nwg & 7;
  const int xcd = (int)blockIdx.x & 7, pos = (int)blockIdx.x >> 3;
  const int wg = (xcd < r ? xcd * (q + 1) : r * (q + 1) + (xcd - r) * q) + pos;
  const int bx = wg / nby, by = wg % nby;

  const int wr = wid >> 2, wc = wid & 3;  // 2 x 4 waves; each owns 128x64 of C

  f32x4 acc[8][4];
#pragma unroll
  for (int m = 0; m < 8; m++)
#pragma unroll
    for (int n = 0; n < 4; n++) acc[m][n] = f32x4{0.f, 0.f, 0.f, 0.f};

  // staging addresses (global source pre-swizzled, LDS dest linear)
  const int j0 = wid * 2, j1 = wid * 2 + 1;
  const int srow = lane >> 2;
  const int skb = (lane & 3) ^ ((lane >> 3) & 3);
  const ushort* gA0 = A + ((size_t)by * 256 + 16 * j0 + srow) * D + skb * 8;
  const ushort* gA1 = A + ((size_t)by * 256 + 16 * j1 + srow) * D + skb * 8;
  const ushort* gB0 = B + ((size_t)bx * 256 + 16 * j0 + srow) * D + skb * 8;
  const ushort* gB1 = B + ((size_t)bx * 256 + 16 * j1 + srow) * D + skb * 8;
  ushort* const lA0 = As + j0 * 512;
  ushort* const lA1 = As + j1 * 512;
  ushort* const lB0 = Bs + j0 * 512;
  ushort* const lB1 = Bs + j1 * 512;

  // fragment read addressing (same swizzle on k-block)
  const int kbx = ((lane >> 4) ^ ((lane >> 1) & 3)) * 8;
  const int a_r0 = wr * 128 + (lane & 15);
  const int b_r0 = wc * 64 + (lane & 15);

  // prologue: stage tiles 0..2; certify t0,t1 (leave t2 in flight); prefetch frags(0)
  STAGE_A(0, 0);
  STAGE_B(0, 0);
  STAGE_A(1, 1);
  STAGE_B(1, 1);
  STAGE_A(2, 2);
  STAGE_B(2, 2);
  asm volatile("s_waitcnt vmcnt(4)" ::: "memory");
  __builtin_amdgcn_s_barrier();

  bf16x8 aA[2][4], bC[2][4];
#pragma unroll
  for (int m = 0; m < 4; ++m) {
    aA[0][m] = AFRAG(0, m);
    bC[0][m] = BFRAG(0, m);
  }

#pragma unroll 1
  for (int tb = 0; tb < 32; tb += 4) {
#pragma unroll
    for (int u = 0; u < 4; ++u) {
      const int t = tb + u;
      const int sc = u;              // t & 3 (tb multiple of 4)
      const int sn = (u + 1) & 3;    // (t+1) & 3
      const int pc = u & 1, pn = (u + 1) & 1;

      if (t < 29) STAGE_A(t + 3, (u + 3) & 3);

      // issue this tile's m=4..7 A-frag reads; they fly during cluster1
      bf16x8 aB0 = AFRAG(sc, 4), aB1 = AFRAG(sc, 5), aB2 = AFRAG(sc, 6), aB3 = AFRAG(sc, 7);

      __builtin_amdgcn_s_setprio(1);
#pragma unroll
      for (int m = 0; m < 4; ++m)
#pragma unroll
        for (int n = 0; n < 4; ++n)
          acc[m][n] = __builtin_amdgcn_mfma_f32_16x16x32_bf16(aA[pc][m], bC[pc][n], acc[m][n], 0, 0, 0);
      __builtin_amdgcn_s_setprio(0);

      if (t < 29) STAGE_B(t + 3, (u + 3) & 3);

      // prefetch next tile's frags; they fly during cluster2
      if (t < 31) {
#pragma unroll
        for (int m = 0; m < 4; ++m) {
          aA[pn][m] = AFRAG(sn, m);
          bC[pn][m] = BFRAG(sn, m);
        }
      }

      __builtin_amdgcn_s_setprio(1);
      acc[4][0] = __builtin_amdgcn_mfma_f32_16x16x32_bf16(aB0, bC[pc][0], acc[4][0], 0, 0, 0);
      acc[4][1] = __builtin_amdgcn_mfma_f32_16x16x32_bf16(aB0, bC[pc][1], acc[4][1], 0, 0, 0);
      acc[4][2] = __builtin_amdgcn_mfma_f32_16x16x32_bf16(aB0, bC[pc][2], acc[4][2], 0, 0, 0);
      acc[4][3] = __builtin_amdgcn_mfma_f32_16x16x32_bf16(aB0, bC[pc][3], acc[4][3], 0, 0, 0);
      acc[5][0] = __builtin_amdgcn_mfma_f32_16x16x32_bf16(aB1, bC[pc][0], acc[5][0], 0, 0, 0);
      acc[5][1] = __builtin_amdgcn_mfma_f32_16x16x32_bf16(aB1, bC[pc][1], acc[5][1], 0, 0, 0);
      acc[5][2] = __builtin_amdgcn_mfma_f32_16x16x32_bf16(aB1, bC[pc][2], acc[5][2], 0, 0, 0);
      acc[5][3] = __builtin_amdgcn_mfma_f32_16x16x32_bf16(aB1, bC[pc][3], acc[5][3], 0, 0, 0);
      acc[6][0] = __builtin_amdgcn_mfma_f32_16x16x32_bf16(aB2, bC[pc][0], acc[6][0], 0, 0, 0);
      acc[6][1] = __builtin_amdgcn_mfma_f32_16x16x32_bf16(aB2, bC[pc][1], acc[6][1], 0, 0, 0);
      acc[6][2] = __builtin_amdgcn_mfma_f32_16x16x32_bf16(aB2, bC[pc][2], acc[6][2], 0, 0, 0);
      acc[6][3] = __builtin_amdgcn_mfma_f32_16x16x32_bf16(aB2, bC[pc][3], acc[6][3], 0, 0, 0);
      acc[7][0] = __builtin_amdgcn_mfma_f32_16x16x32_bf16(aB3, bC[pc][0], acc[7][0], 0, 0, 0);
      acc[7][1] = __builtin_amdgcn_mfma_f32_16x16x32_bf16(aB3, bC[pc][1], acc[7][1], 0, 0, 0);
      acc[7][2] = __builtin_amdgcn_mfma_f32_16x16x32_bf16(aB3, bC[pc][2], acc[7][2], 0, 0, 0);
      acc[7][3] = __builtin_amdgcn_mfma_f32_16x16x32_bf16(aB3, bC[pc][3], acc[7][3], 0, 0, 0);
      __builtin_amdgcn_s_setprio(0);

      // certify slot t+2 for all waves before anyone reads it during t+1
      if (t < 29) asm volatile("s_waitcnt vmcnt(4)" ::: "memory");
      else if (t == 29) asm volatile("s_waitcnt vmcnt(0)" ::: "memory");
      __builtin_amdgcn_s_barrier();
    }
  }

  // C/D layout: row = (lane>>4)*4 + j, col = lane&15
  const size_t crow = (size_t)by * 256 + wr * 128 + ((lane >> 4) << 2);
  const size_t ccol = (size_t)bx * 256 + wc * 64 + (lane & 15);
#pragma unroll
  for (int m = 0; m < 8; m++)
#pragma unroll
    for (int n = 0; n < 4; n++)
#pragma unroll
      for (int j = 0; j < 4; j++)
        C[(crow + m * 16 + j) * (size_t)NM + ccol + n * 16] = f2bf(acc[m][n][j]);
}

// ---------- top-32: max -> near-max candidate filter -> 1-wave select ----------
#define CAP2 1024
__global__ __launch_bounds__(512) void topk_k(const ushort* __restrict__ scores, int row_base,
                                              const float* __restrict__ temp,
                                              float* __restrict__ attn,
                                              int* __restrict__ idx_out) {
  const int lrow = blockIdx.x;
  const int grow = row_base + lrow;
  const int tid = threadIdx.x;
  const int lane = tid & 63, wid = tid >> 6;
  __shared__ unsigned red[8];
  __shared__ int cnt_s;
  __shared__ unsigned ckey[CAP2];
  __shared__ unsigned cand64[64];
  __shared__ unsigned okey[TOPK];
  __shared__ int oidx[TOPK];

  const uint4* row4 = (const uint4*)(scores + (size_t)lrow * NM);
  unsigned kreg[32];
#pragma unroll
  for (int j = 0; j < 8; ++j) {
    const uint4 w = row4[tid + 512 * j];
    const unsigned wv[4] = {w.x, w.y, w.z, w.w};
#pragma unroll
    for (int p = 0; p < 4; ++p) {
      const unsigned u = wv[p];
      const unsigned m = (u >> 15) & 0x00010001u;
      kreg[j * 4 + p] = u ^ (m * 0x7FFFu + 0x80008000u);
    }
  }

  unsigned mhi = 0, mlo = 0;
#pragma unroll
  for (int r = 0; r < 32; ++r) {
    mhi = max(mhi, kreg[r] & 0xFFFF0000u);
    mlo = max(mlo, kreg[r] << 16);
  }
  unsigned tmax = max(mhi, mlo) >> 16;
#pragma unroll
  for (int off = 32; off; off >>= 1) tmax = max(tmax, __shfl_xor(tmax, off, 64));
  if (lane == 0) red[wid] = tmax;
  if (tid == 0) cnt_s = 0;
  __syncthreads();
  unsigned M = red[0];
#pragma unroll
  for (int w = 1; w < 8; ++w) M = max(M, red[w]);

  unsigned t0 = (M > 128) ? (M - 128) : 0u;
  int cnt = 0;
  for (int att = 0; att < 18; ++att) {
#pragma unroll
    for (int j = 0; j < 8; ++j) {
#pragma unroll
      for (int p = 0; p < 4; ++p) {
        const unsigned kk = kreg[j * 4 + p];
        const unsigned klo = kk & 0xFFFFu, khi = kk >> 16;
        const int base = (tid + 512 * j) * 8 + p * 2;
        if (klo >= t0) {
          const int q = atomicAdd(&cnt_s, 1);
          if (q < CAP2) ckey[q] = (klo << 16) | (unsigned)(32767 - base);
        }
        if (khi >= t0) {
          const int q = atomicAdd(&cnt_s, 1);
          if (q < CAP2) ckey[q] = (khi << 16) | (unsigned)(32767 - (base + 1));
        }
      }
    }
    __syncthreads();
    cnt = cnt_s;
    __syncthreads();
    if ((cnt >= TOPK && cnt <= CAP2) || att == 17) break;
    if (cnt < TOPK) t0 >>= 1;
    else t0 = t0 + ((M - t0 + 1) >> 1);
    if (tid == 0) cnt_s = 0;
    __syncthreads();
  }
  const int n = min(cnt, CAP2);

  if (tid < 64) {
    unsigned lo = t0, hi = M;
    while (lo < hi) {
      const unsigned mid = (lo + hi + 1) >> 1;
      int c = 0;
      for (int i = lane; i < n; i += 64) c += (int)((ckey[i] >> 16) >= mid);
#pragma unroll
      for (int off = 32; off; off >>= 1) c += __shfl_xor(c, off, 64);
      if (c >= TOPK) lo = mid; else hi = mid - 1;
    }
    const unsigned t32 = lo;
    int c32 = 0;
    for (int i = lane; i < n; i += 64) c32 += (int)((ckey[i] >> 16) >= t32);
#pragma unroll
    for (int off = 32; off; off >>= 1) c32 += __shfl_xor(c32, off, 64);

    if (c32 <= 64) {
      cand64[lane] = 0;
      int base = 0;
      for (int r0 = 0; r0 < n; r0 += 64) {
        const int i = r0 + lane;
        const unsigned k = (i < n) ? ckey[i] : 0u;
        const bool p = (k >> 16) >= t32;
        const unsigned long long bm = __ballot(p);
        if (p) {
          const int pos = base + __popcll(bm & ((1ull << lane) - 1ull));
          if (pos < 64) cand64[pos] = k;
        }
        base += __popcll(bm);
      }
      unsigned v = cand64[lane];
#pragma unroll
      for (int k2 = 2; k2 <= 64; k2 <<= 1) {
#pragma unroll
        for (int j = k2 >> 1; j > 0; j >>= 1) {
          const unsigned o = __shfl_xor(v, j, 64);
          const bool lower = (lane & j) == 0;
          const bool descB = (lane & k2) == 0;
          const unsigned mx = v > o ? v : o;
          const unsigned mn = v > o ? o : v;
          v = (lower == descB) ? mx : mn;
        }
      }
      if (lane < TOPK) {
        okey[lane] = v >> 16;
        oidx[lane] = 32767 - (int)(v & 0x7FFFu);
      }
    } else {
      for (int k = 0; k < TOPK; ++k) {
        unsigned bk = 0;
        for (int j = lane; j < n; j += 64) bk = max(bk, ckey[j]);
#pragma unroll
        for (int off = 32; off; off >>= 1) bk = max(bk, __shfl_xor(bk, off, 64));
        if (lane == 0) {
          okey[k] = bk >> 16;
          oidx[k] = 32767 - (int)(bk & 0x7FFFu);
        }
        for (int j = lane; j < n; j += 64)
          if (ckey[j] == bk) ckey[j] = 0;
      }
    }
  }
  __syncthreads();

  if (tid < TOPK) {
    const float T = fabsf(temp[0]);
    const unsigned k0 = okey[tid];
    const unsigned u0 = (k0 & 0x8000u) ? (k0 ^ 0x8000u) : (k0 ^ 0xFFFFu);
    const unsigned km = okey[0];
    const unsigned um = (km & 0x8000u) ? (km ^ 0x8000u) : (km ^ 0xFFFFu);
    const float s = __uint_as_float(u0 << 16) * T;
    const float mx = __uint_as_float(um << 16) * T;
    const float e = __expf(s - mx);
    float sum = e;
#pragma unroll
    for (int off = 16; off; off >>= 1) sum += __shfl_xor(sum, off, 32);
    attn[(size_t)grow * TOPK + tid] = e / sum;
    idx_out[(size_t)grow * TOPK + tid] = oidx[tid];
  }
}

// ---------- gather values + residual + LayerNorm ----------
__global__ __launch_bounds__(256) void gather_ln_k(const float* __restrict__ V,
                                                   const float* __restrict__ Q,
                                                   const float* __restrict__ gamma,
                                                   const float* __restrict__ beta,
                                                   const float* __restrict__ attn,
                                                   const int* __restrict__ idx,
                                                   float* __restrict__ out) {
  const int row = blockIdx.x, tid = threadIdx.x;
  __shared__ float a_s[TOPK];
  __shared__ int i_s[TOPK];
  __shared__ float redS[4], redQ[4];
  if (tid < TOPK) {
    a_s[tid] = attn[(size_t)row * TOPK + tid];
    i_s[tid] = idx[(size_t)row * TOPK + tid];
  }
  __syncthreads();
  float4 acc = {0.f, 0.f, 0.f, 0.f};
#pragma unroll
  for (int kb = 0; kb < TOPK; kb += 8) {
    float4 v[8];
#pragma unroll
    for (int u = 0; u < 8; ++u)
      v[u] = ((const float4*)(V + (size_t)i_s[kb + u] * D))[tid];
#pragma unroll
    for (int u = 0; u < 8; ++u) {
      const float a = a_s[kb + u];
      acc.x = fmaf(a, v[u].x, acc.x);
      acc.y = fmaf(a, v[u].y, acc.y);
      acc.z = fmaf(a, v[u].z, acc.z);
      acc.w = fmaf(a, v[u].w, acc.w);
    }
  }
  const float4 q = ((const float4*)(Q + (size_t)row * D))[tid];
  float4 x = {acc.x + q.x, acc.y + q.y, acc.z + q.z, acc.w + q.w};
  float s = x.x + x.y + x.z + x.w;
  float ss = x.x * x.x + x.y * x.y + x.z * x.z + x.w * x.w;
#pragma unroll
  for (int off = 32; off; off >>= 1) {
    s += __shfl_xor(s, off, 64);
    ss += __shfl_xor(ss, off, 64);
  }
  const int wid = tid >> 6, lane = tid & 63;
  if (lane == 0) { redS[wid] = s; redQ[wid] = ss; }
  __syncthreads();
  const float S = redS[0] + redS[1] + redS[2] + redS[3];
  const float SS = redQ[0] + redQ[1] + redQ[2] + redQ[3];
  const float mu = S * (1.0f / D);
  const float var = SS * (1.0f / D) - mu * mu;
  const float rstd = rsqrtf(var + 1e-5f);
  const float4 g = ((const float4*)gamma)[tid];
  const float4 b = ((const float4*)beta)[tid];
  float4 o;
  o.x = (x.x - mu) * rstd * g.x + b.x;
  o.y = (x.y - mu) * rstd * g.y + b.y;
  o.z = (x.z - mu) * rstd * g.z + b.z;
  o.w = (x.w - mu) * rstd * g.w + b.w;
  ((float4*)(out + (size_t)row * D))[tid] = o;
}

extern "C" void kernel_launch(void* const* d_in, const int* in_sizes, int n_in,
                              void* d_out, int out_size, void* d_ws, size_t ws_size,
                              hipStream_t stream) {
  const float* Q = (const float*)d_in[0];
  const float* K = (const float*)d_in[1];
  const float* V = (const float*)d_in[2];
  const float* T = (const float*)d_in[3];
  const float* G = (const float*)d_in[4];
  const float* Bt = (const float*)d_in[5];
  float* out = (float*)d_out;
  float* attn = out + (size_t)NQ * D;

  char* ws = (char*)d_ws;
  const size_t off_qn = 0;
  const size_t off_kn = off_qn + (size_t)NQ * D * 2;
  const size_t off_idx = off_kn + (size_t)NM * D * 2;
  const size_t off_sc = off_idx + (size_t)NQ * TOPK * sizeof(int);
  ushort* qn = (ushort*)(ws + off_qn);
  ushort* kn = (ushort*)(ws + off_kn);
  int* idx = (int*)(ws + off_idx);
  ushort* scores = (ushort*)(ws + off_sc);

  const size_t avail = ws_size > off_sc ? ws_size - off_sc : 0;
  int slice = 2048;
  while (slice > 256 && (size_t)slice * NM * 2ull > avail) slice >>= 1;

  norm_cast_k<<<NQ, 256, 0, stream>>>(Q, qn);
  norm_cast_k<<<NM, 256, 0, stream>>>(K, kn);

  const int nbx = NM / 256;
  for (int s0 = 0; s0 < NQ; s0 += slice) {
    const int nby = slice / 256;
    gemm256<<<nbx * nby, 512, 0, stream>>>(qn + (size_t)s0 * D, kn, scores, nby);
    topk_k<<<slice, 512, 0, stream>>>(scores, s0, T, attn, idx);
  }
  gather_ln_k<<<NQ, 256, 0, stream>>>(V, Q, G, Bt, attn, idx, out);
}

// Round 7
// 1009.012 us; speedup vs baseline: 1.3717x; 1.3698x over previous
//
#include <hip/hip_runtime.h>
#include <hip/hip_bf16.h>

#define D 1024
#define NQ 8192
#define NM 32768
#define TOPK 32
#define NBX (NM / 256)  // 128 col-tiles

typedef __attribute__((ext_vector_type(8))) __bf16 bf16x8;
typedef __attribute__((ext_vector_type(4))) float f32x4;

__device__ __forceinline__ void load_lds16(const void* g, void* l) {
  __builtin_amdgcn_global_load_lds(
      (const __attribute__((address_space(1))) void*)g,
      (__attribute__((address_space(3))) void*)l, 16, 0, 0);
}

__device__ __forceinline__ ushort f2bf(float f) {
  unsigned u = __float_as_uint(f);
  unsigned r = (u + 0x7FFFu + ((u >> 16) & 1u)) >> 16;
  return (ushort)r;
}
// monotonic 16-bit key for a bf16 pattern
__device__ __forceinline__ unsigned key16(unsigned u) {
  return u ^ ((u & 0x8000u) ? 0xFFFFu : 0x8000u);
}

// ---------- row L2-normalize f32 -> bf16 ----------
__global__ __launch_bounds__(256) void norm_cast_k(const float* __restrict__ in,
                                                   ushort* __restrict__ out) {
  const int row = blockIdx.x;
  const int tid = threadIdx.x;
  const float4 v = ((const float4*)(in + (size_t)row * D))[tid];
  float ss = v.x * v.x + v.y * v.y + v.z * v.z + v.w * v.w;
#pragma unroll
  for (int off = 32; off; off >>= 1) ss += __shfl_xor(ss, off, 64);
  __shared__ float wsum[4];
  const int wid = tid >> 6, lane = tid & 63;
  if (lane == 0) wsum[wid] = ss;
  __syncthreads();
  const float tot = wsum[0] + wsum[1] + wsum[2] + wsum[3];
  const float inv = 1.0f / fmaxf(sqrtf(tot), 1e-12f);
  ushort4 o;
  o.x = f2bf(v.x * inv);
  o.y = f2bf(v.y * inv);
  o.z = f2bf(v.z * inv);
  o.w = f2bf(v.w * inv);
  ((ushort4*)(out + (size_t)row * D))[tid] = o;
}

// ---------- 256x256 bf16 GEMM (R4 structure: ring-4, 2 barriers/tile) ----------
// + fused per-(row, col-tile) max epilogue for top-k prefiltering.
#define SLOTU 8192  // ushorts per operand per ring slot (256x32)

__global__ __launch_bounds__(512, 2) void gemm256(const ushort* __restrict__ A,
                                                  const ushort* __restrict__ B,
                                                  ushort* __restrict__ C,
                                                  ushort* __restrict__ TM,  // [NBX][srows]
                                                  int nby, int srows) {
  __shared__ alignas(16) ushort As[4 * SLOTU];
  __shared__ alignas(16) ushort Bs[4 * SLOTU];
  __shared__ unsigned umax[256];
  const int tid = threadIdx.x;
  const int lane = tid & 63, wid = tid >> 6;
  if (tid < 256) umax[tid] = 0;

  // T1: bijective XCD swizzle on flat grid
  const int nwg = (int)gridDim.x;
  const int q = nwg >> 3, r = nwg & 7;
  const int xcd = (int)blockIdx.x & 7, pos = (int)blockIdx.x >> 3;
  const int wg = (xcd < r ? xcd * (q + 1) : r * (q + 1) + (xcd - r) * q) + pos;
  const int bx = wg / nby, by = wg % nby;

  const int wr = wid >> 2, wc = wid & 3;  // 2 x 4 waves; each owns 128x64 of C

  f32x4 acc[8][4];
#pragma unroll
  for (int m = 0; m < 8; m++)
#pragma unroll
    for (int n = 0; n < 4; n++) acc[m][n] = f32x4{0.f, 0.f, 0.f, 0.f};

  // staging: wave stages stripes j0,j1 (16 rows x 32 cols) of A and B.
  // T2: global source pre-swizzled; LDS dest linear.
  const int j0 = wid * 2, j1 = wid * 2 + 1;
  const int srow = lane >> 2;
  const int skb = (lane & 3) ^ ((lane >> 3) & 3);
  const ushort* gA0 = A + ((size_t)by * 256 + 16 * j0 + srow) * D + skb * 8;
  const ushort* gA1 = A + ((size_t)by * 256 + 16 * j1 + srow) * D + skb * 8;
  const ushort* gB0 = B + ((size_t)bx * 256 + 16 * j0 + srow) * D + skb * 8;
  const ushort* gB1 = B + ((size_t)bx * 256 + 16 * j1 + srow) * D + skb * 8;
  ushort* const lA0 = As + j0 * 512;
  ushort* const lA1 = As + j1 * 512;
  ushort* const lB0 = Bs + j0 * 512;
  ushort* const lB1 = Bs + j1 * 512;

  // fragment reads apply the same swizzle on the k-block
  const int kbx = ((lane >> 4) ^ ((lane >> 1) & 3)) * 8;
  const int a_r0 = wr * 128 + (lane & 15);
  const int b_r0 = wc * 64 + (lane & 15);

  // prologue: stage tiles 0..2; wait tile 0 (keep 8 in flight)
#pragma unroll
  for (int t = 0; t < 3; ++t) {
    const int ss = t * SLOTU;
    load_lds16(gA0 + t * 32, lA0 + ss);
    load_lds16(gA1 + t * 32, lA1 + ss);
    load_lds16(gB0 + t * 32, lB0 + ss);
    load_lds16(gB1 + t * 32, lB1 + ss);
  }
  asm volatile("s_waitcnt vmcnt(8)" ::: "memory");
  __builtin_amdgcn_s_barrier();

#pragma unroll 1
  for (int t = 0; t < 32; ++t) {
    const int sb = (t & 3) * SLOTU;
    bf16x8 afr[4], bfr[4];
    // ---- phase A: frags m=0..3 + all B frags; stage A-stripes of t+3
#pragma unroll
    for (int m = 0; m < 4; ++m)
      afr[m] = *(const bf16x8*)&As[sb + (a_r0 + m * 16) * 32 + kbx];
#pragma unroll
    for (int n = 0; n < 4; ++n)
      bfr[n] = *(const bf16x8*)&Bs[sb + (b_r0 + n * 16) * 32 + kbx];
    if (t < 29) {
      const int ss = ((t + 3) & 3) * SLOTU;
      load_lds16(gA0 + (t + 3) * 32, lA0 + ss);
      load_lds16(gA1 + (t + 3) * 32, lA1 + ss);
    }
    __builtin_amdgcn_s_barrier();
    __builtin_amdgcn_s_setprio(1);
#pragma unroll
    for (int m = 0; m < 4; ++m)
#pragma unroll
      for (int n = 0; n < 4; ++n)
        acc[m][n] = __builtin_amdgcn_mfma_f32_16x16x32_bf16(afr[m], bfr[n], acc[m][n], 0, 0, 0);
    __builtin_amdgcn_s_setprio(0);
    __builtin_amdgcn_s_barrier();
    // ---- phase B: frags m=4..7 (B frags reused); stage B-stripes of t+3
#pragma unroll
    for (int m = 0; m < 4; ++m)
      afr[m] = *(const bf16x8*)&As[sb + (a_r0 + 64 + m * 16) * 32 + kbx];
    if (t < 29) {
      const int ss = ((t + 3) & 3) * SLOTU;
      load_lds16(gB0 + (t + 3) * 32, lB0 + ss);
      load_lds16(gB1 + (t + 3) * 32, lB1 + ss);
    }
    __builtin_amdgcn_s_barrier();
    __builtin_amdgcn_s_setprio(1);
#pragma unroll
    for (int m = 0; m < 4; ++m)
#pragma unroll
      for (int n = 0; n < 4; ++n)
        acc[m + 4][n] = __builtin_amdgcn_mfma_f32_16x16x32_bf16(afr[m], bfr[n], acc[m + 4][n], 0, 0, 0);
    __builtin_amdgcn_s_setprio(0);
    if (t < 29) asm volatile("s_waitcnt vmcnt(8)" ::: "memory");
    else if (t == 29) asm volatile("s_waitcnt vmcnt(4)" ::: "memory");
    else if (t == 30) asm volatile("s_waitcnt vmcnt(0)" ::: "memory");
    __builtin_amdgcn_s_barrier();
  }

  // epilogue part 1: per-(local row) max over this block's 256 cols
  // local row = wr*128 + (lane>>4)*4 + m*16 + j  (same for lanes sharing lane>>4)
  const int lr0 = wr * 128 + ((lane >> 4) << 2);
#pragma unroll
  for (int m = 0; m < 8; m++)
#pragma unroll
    for (int j = 0; j < 4; j++) {
      float fm = fmaxf(fmaxf(acc[m][0][j], acc[m][1][j]), fmaxf(acc[m][2][j], acc[m][3][j]));
      atomicMax(&umax[lr0 + m * 16 + j], key16((unsigned)f2bf(fm)));
    }
  __syncthreads();
  if (tid < 256) TM[(size_t)bx * srows + by * 256 + tid] = (ushort)umax[tid];

  // epilogue part 2: C-write. layout: row = (lane>>4)*4 + j, col = lane&15
  const size_t crow = (size_t)by * 256 + wr * 128 + ((lane >> 4) << 2);
  const size_t ccol = (size_t)bx * 256 + wc * 64 + (lane & 15);
#pragma unroll
  for (int m = 0; m < 8; m++)
#pragma unroll
    for (int n = 0; n < 4; n++)
#pragma unroll
      for (int j = 0; j < 4; j++)
        C[(crow + m * 16 + j) * (size_t)NM + ccol + n * 16] = f2bf(acc[m][n][j]);
}

// ---------- top-32 with tile-max prefilter ----------
#define CAP2 1024
__global__ __launch_bounds__(512) void topk_k(const ushort* __restrict__ scores,
                                              const ushort* __restrict__ tmax,  // [NBX][srows] keys
                                              int srows, int row_base,
                                              const float* __restrict__ temp,
                                              float* __restrict__ attn,
                                              int* __restrict__ idx_out) {
  const int lrow = blockIdx.x;
  const int grow = row_base + lrow;
  const int tid = threadIdx.x;
  const int lane = tid & 63, wid = tid >> 6;
  __shared__ unsigned tlb_s, M_s;
  __shared__ int nqt_s, cnt_s;
  __shared__ ushort qt[NBX];
  __shared__ unsigned ckey[CAP2];
  __shared__ unsigned cand64[64];
  __shared__ unsigned okey[TOPK];
  __shared__ int oidx[TOPK];

  if (tid == 0) cnt_s = 0;

  // ---- step 1 (wave 0): t_lb = 32nd-largest tile-max (sound lower bound for
  // the global 32nd value); build qualifying-tile list (tmax >= t_lb).
  if (tid < 64) {
    const unsigned ka = tmax[(size_t)lane * srows + lrow];
    const unsigned kb = tmax[(size_t)(lane + 64) * srows + lrow];
    unsigned mx = max(ka, kb);
#pragma unroll
    for (int off = 32; off; off >>= 1) mx = max(mx, __shfl_xor(mx, off, 64));
    unsigned lo = 0, hi = mx;
    while (lo < hi) {
      const unsigned mid = (lo + hi + 1) >> 1;
      int c = (int)(ka >= mid) + (int)(kb >= mid);
#pragma unroll
      for (int off = 32; off; off >>= 1) c += __shfl_xor(c, off, 64);
      if (c >= TOPK) lo = mid; else hi = mid - 1;
    }
    const bool pa = ka >= lo;
    unsigned long long bm = __ballot(pa);
    if (pa) qt[__popcll(bm & ((1ull << lane) - 1ull))] = (ushort)lane;
    int base = __popcll(bm);
    const bool pb = kb >= lo;
    bm = __ballot(pb);
    if (pb) qt[base + __popcll(bm & ((1ull << lane) - 1ull))] = (ushort)(lane + 64);
    base += __popcll(bm);
    if (lane == 0) { nqt_s = base; tlb_s = lo; M_s = mx; }
  }
  __syncthreads();
  const unsigned M = M_s;
  const int nqt = nqt_s;
  unsigned t0 = tlb_s;
  unsigned tlo = t0, thi = M;

  // ---- step 2: collect candidates >= t0 from qualifying tiles only
  const unsigned* rowu = (const unsigned*)(scores + (size_t)lrow * NM);
  int cnt = 0;
  for (int att = 0; att < 18; ++att) {
    for (int i = wid; i < nqt; i += 8) {
      const int tb = qt[i];
#pragma unroll
      for (int p = 0; p < 2; ++p) {
        const unsigned u = rowu[tb * 128 + lane * 2 + p];
        const unsigned m = (u >> 15) & 0x00010001u;
        const unsigned kk = u ^ (m * 0x7FFFu + 0x80008000u);
        const unsigned klo = kk & 0xFFFFu, khi = kk >> 16;
        const int bidx = tb * 256 + (lane * 2 + p) * 2;
        if (klo >= t0) { const int qq = atomicAdd(&cnt_s, 1); if (qq < CAP2) ckey[qq] = (klo << 16) | (unsigned)(32767 - bidx); }
        if (khi >= t0) { const int qq = atomicAdd(&cnt_s, 1); if (qq < CAP2) ckey[qq] = (khi << 16) | (unsigned)(32767 - (bidx + 1)); }
      }
    }
    __syncthreads();
    cnt = cnt_s;
    __syncthreads();
    if ((cnt >= TOPK && cnt <= CAP2) || att == 17) break;
    if (cnt > CAP2) { tlo = t0; t0 = t0 + ((thi - t0 + 1) >> 1); }  // raise
    else { thi = t0; t0 = tlo + ((t0 - tlo) >> 1); }                // bracket down
    if (tid == 0) cnt_s = 0;
    __syncthreads();
  }
  const int n = min(cnt, CAP2);

  // ---- step 3 (wave 0): exact 32nd threshold, compact, bitonic sort, softmax
  if (tid < 64) {
    unsigned lo = t0, hi = M;
    while (lo < hi) {
      const unsigned mid = (lo + hi + 1) >> 1;
      int c = 0;
      for (int i = lane; i < n; i += 64) c += (int)((ckey[i] >> 16) >= mid);
#pragma unroll
      for (int off = 32; off; off >>= 1) c += __shfl_xor(c, off, 64);
      if (c >= TOPK) lo = mid; else hi = mid - 1;
    }
    const unsigned t32 = lo;
    int c32 = 0;
    for (int i = lane; i < n; i += 64) c32 += (int)((ckey[i] >> 16) >= t32);
#pragma unroll
    for (int off = 32; off; off >>= 1) c32 += __shfl_xor(c32, off, 64);

    if (c32 <= 64) {
      cand64[lane] = 0;
      int base = 0;
      for (int r0 = 0; r0 < n; r0 += 64) {
        const int i = r0 + lane;
        const unsigned k = (i < n) ? ckey[i] : 0u;
        const bool p = (k >> 16) >= t32;
        const unsigned long long bm = __ballot(p);
        if (p) {
          const int ps = base + __popcll(bm & ((1ull << lane) - 1ull));
          if (ps < 64) cand64[ps] = k;
        }
        base += __popcll(bm);
      }
      unsigned v = cand64[lane];
#pragma unroll
      for (int k2 = 2; k2 <= 64; k2 <<= 1) {
#pragma unroll
        for (int j = k2 >> 1; j > 0; j >>= 1) {
          const unsigned o = __shfl_xor(v, j, 64);
          const bool lower = (lane & j) == 0;
          const bool descB = (lane & k2) == 0;
          const unsigned mxv = v > o ? v : o;
          const unsigned mnv = v > o ? o : v;
          v = (lower == descB) ? mxv : mnv;
        }
      }
      if (lane < TOPK) {
        okey[lane] = v >> 16;
        oidx[lane] = 32767 - (int)(v & 0x7FFFu);
      }
    } else {
      for (int k = 0; k < TOPK; ++k) {
        unsigned bk = 0;
        for (int j = lane; j < n; j += 64) bk = max(bk, ckey[j]);
#pragma unroll
        for (int off = 32; off; off >>= 1) bk = max(bk, __shfl_xor(bk, off, 64));
        if (lane == 0) {
          okey[k] = bk >> 16;
          oidx[k] = 32767 - (int)(bk & 0x7FFFu);
        }
        for (int j = lane; j < n; j += 64)
          if (ckey[j] == bk) ckey[j] = 0;
      }
    }
  }
  __syncthreads();

  if (tid < TOPK) {
    const float T = fabsf(temp[0]);
    const unsigned k0 = okey[tid];
    const unsigned u0 = (k0 & 0x8000u) ? (k0 ^ 0x8000u) : (k0 ^ 0xFFFFu);
    const unsigned km = okey[0];
    const unsigned um = (km & 0x8000u) ? (km ^ 0x8000u) : (km ^ 0xFFFFu);
    const float s = __uint_as_float(u0 << 16) * T;
    const float mx = __uint_as_float(um << 16) * T;
    const float e = __expf(s - mx);
    float sum = e;
#pragma unroll
    for (int off = 16; off; off >>= 1) sum += __shfl_xor(sum, off, 32);
    attn[(size_t)grow * TOPK + tid] = e / sum;
    idx_out[(size_t)grow * TOPK + tid] = oidx[tid];
  }
}

// ---------- gather values + residual + LayerNorm ----------
__global__ __launch_bounds__(256) void gather_ln_k(const float* __restrict__ V,
                                                   const float* __restrict__ Q,
                                                   const float* __restrict__ gamma,
                                                   const float* __restrict__ beta,
                                                   const float* __restrict__ attn,
                                                   const int* __restrict__ idx,
                                                   float* __restrict__ out) {
  const int row = blockIdx.x, tid = threadIdx.x;
  __shared__ float a_s[TOPK];
  __shared__ int i_s[TOPK];
  __shared__ float redS[4], redQ[4];
  if (tid < TOPK) {
    a_s[tid] = attn[(size_t)row * TOPK + tid];
    i_s[tid] = idx[(size_t)row * TOPK + tid];
  }
  __syncthreads();
  float4 acc = {0.f, 0.f, 0.f, 0.f};
#pragma unroll
  for (int kb = 0; kb < TOPK; kb += 8) {
    float4 v[8];
#pragma unroll
    for (int u = 0; u < 8; ++u)
      v[u] = ((const float4*)(V + (size_t)i_s[kb + u] * D))[tid];
#pragma unroll
    for (int u = 0; u < 8; ++u) {
      const float a = a_s[kb + u];
      acc.x = fmaf(a, v[u].x, acc.x);
      acc.y = fmaf(a, v[u].y, acc.y);
      acc.z = fmaf(a, v[u].z, acc.z);
      acc.w = fmaf(a, v[u].w, acc.w);
    }
  }
  const float4 q = ((const float4*)(Q + (size_t)row * D))[tid];
  float4 x = {acc.x + q.x, acc.y + q.y, acc.z + q.z, acc.w + q.w};
  float s = x.x + x.y + x.z + x.w;
  float ss = x.x * x.x + x.y * x.y + x.z * x.z + x.w * x.w;
#pragma unroll
  for (int off = 32; off; off >>= 1) {
    s += __shfl_xor(s, off, 64);
    ss += __shfl_xor(ss, off, 64);
  }
  const int wid = tid >> 6, lane = tid & 63;
  if (lane == 0) { redS[wid] = s; redQ[wid] = ss; }
  __syncthreads();
  const float S = redS[0] + redS[1] + redS[2] + redS[3];
  const float SS = redQ[0] + redQ[1] + redQ[2] + redQ[3];
  const float mu = S * (1.0f / D);
  const float var = SS * (1.0f / D) - mu * mu;
  const float rstd = rsqrtf(var + 1e-5f);
  const float4 g = ((const float4*)gamma)[tid];
  const float4 b = ((const float4*)beta)[tid];
  float4 o;
  o.x = (x.x - mu) * rstd * g.x + b.x;
  o.y = (x.y - mu) * rstd * g.y + b.y;
  o.z = (x.z - mu) * rstd * g.z + b.z;
  o.w = (x.w - mu) * rstd * g.w + b.w;
  ((float4*)(out + (size_t)row * D))[tid] = o;
}

extern "C" void kernel_launch(void* const* d_in, const int* in_sizes, int n_in,
                              void* d_out, int out_size, void* d_ws, size_t ws_size,
                              hipStream_t stream) {
  const float* Q = (const float*)d_in[0];
  const float* K = (const float*)d_in[1];
  const float* V = (const float*)d_in[2];
  const float* T = (const float*)d_in[3];
  const float* G = (const float*)d_in[4];
  const float* Bt = (const float*)d_in[5];
  float* out = (float*)d_out;
  float* attn = out + (size_t)NQ * D;

  char* ws = (char*)d_ws;
  const size_t off_qn = 0;
  const size_t off_kn = off_qn + (size_t)NQ * D * 2;
  const size_t off_idx = off_kn + (size_t)NM * D * 2;
  const size_t off_tm = off_idx + (size_t)NQ * TOPK * sizeof(int);
  const size_t off_sc = off_tm + (size_t)NBX * 2048 * 2;
  ushort* qn = (ushort*)(ws + off_qn);
  ushort* kn = (ushort*)(ws + off_kn);
  int* idx = (int*)(ws + off_idx);
  ushort* tm = (ushort*)(ws + off_tm);
  ushort* scores = (ushort*)(ws + off_sc);

  const size_t avail = ws_size > off_sc ? ws_size - off_sc : 0;
  int slice = 2048;
  while (slice > 256 && (size_t)slice * NM * 2ull > avail) slice >>= 1;

  norm_cast_k<<<NQ, 256, 0, stream>>>(Q, qn);
  norm_cast_k<<<NM, 256, 0, stream>>>(K, kn);

  const int nbx = NM / 256;
  for (int s0 = 0; s0 < NQ; s0 += slice) {
    const int nby = slice / 256;
    gemm256<<<nbx * nby, 512, 0, stream>>>(qn + (size_t)s0 * D, kn, scores, tm, nby, slice);
    topk_k<<<slice, 512, 0, stream>>>(scores, tm, slice, s0, T, attn, idx);
  }
  gather_ln_k<<<NQ, 256, 0, stream>>>(V, Q, G, Bt, attn, idx, out);
}

// Round 8
// 972.537 us; speedup vs baseline: 1.4231x; 1.0375x over previous
//
#include <hip/hip_runtime.h>
#include <hip/hip_bf16.h>

#define D 1024
#define NQ 8192
#define NM 32768
#define TOPK 32
#define NBX (NM / 256)

typedef __attribute__((ext_vector_type(8))) __bf16 bf16x8;
typedef __attribute__((ext_vector_type(4))) float f32x4;

__device__ __forceinline__ void load_lds16(const void* g, void* l) {
  __builtin_amdgcn_global_load_lds(
      (const __attribute__((address_space(1))) void*)g,
      (__attribute__((address_space(3))) void*)l, 16, 0, 0);
}

__device__ __forceinline__ ushort f2bf(float f) {
  unsigned u = __float_as_uint(f);
  unsigned r = (u + 0x7FFFu + ((u >> 16) & 1u)) >> 16;
  return (ushort)r;
}
__device__ __forceinline__ unsigned key16(unsigned u) {
  return u ^ ((u & 0x8000u) ? 0xFFFFu : 0x8000u);
}

// ---------- row L2-normalize f32 -> bf16 ----------
__global__ __launch_bounds__(256) void norm_cast_k(const float* __restrict__ in,
                                                   ushort* __restrict__ out) {
  const int row = blockIdx.x;
  const int tid = threadIdx.x;
  const float4 v = ((const float4*)(in + (size_t)row * D))[tid];
  float ss = v.x * v.x + v.y * v.y + v.z * v.z + v.w * v.w;
#pragma unroll
  for (int off = 32; off; off >>= 1) ss += __shfl_xor(ss, off, 64);
  __shared__ float wsum[4];
  const int wid = tid >> 6, lane = tid & 63;
  if (lane == 0) wsum[wid] = ss;
  __syncthreads();
  const float tot = wsum[0] + wsum[1] + wsum[2] + wsum[3];
  const float inv = 1.0f / fmaxf(sqrtf(tot), 1e-12f);
  ushort4 o;
  o.x = f2bf(v.x * inv);
  o.y = f2bf(v.y * inv);
  o.z = f2bf(v.z * inv);
  o.w = f2bf(v.w * inv);
  ((ushort4*)(out + (size_t)row * D))[tid] = o;
}

// ---------- 256x256 bf16 GEMM, BK=64 8-phase derived-waits schedule ----------
// LDS: As/Bs [2 dbuf][2 half][128 rows][64 cols] bf16 = 64KB each.
// Per K-tile (4 phases): quadrants (m03,n01)(m03,n23)(m47,n23)(m47,n01).
// Stage stream: p0->B1(kt+1), p1->A1(kt+1), p2->B0(kt+2), p3->A0(kt+2);
// one counted vmcnt(4) at p3 certifies all of kt+1 (2 halves stay in flight).
__global__ __launch_bounds__(512, 2) void gemm256(const ushort* __restrict__ A,
                                                  const ushort* __restrict__ B,
                                                  ushort* __restrict__ C,
                                                  ushort* __restrict__ TM,
                                                  int nby, int srows) {
  __shared__ alignas(16) ushort As[2 * 2 * 8192];
  __shared__ alignas(16) ushort Bs[2 * 2 * 8192];
  __shared__ float wmax[4][256];
  const int tid = threadIdx.x;
  const int lane = tid & 63, wid = tid >> 6;
  const int l15 = lane & 15, l4 = lane >> 4;

  // T1: bijective XCD swizzle
  const int nwg = (int)gridDim.x;
  const int q = nwg >> 3, r = nwg & 7;
  const int xcd = (int)blockIdx.x & 7, pos = (int)blockIdx.x >> 3;
  const int wg = (xcd < r ? xcd * (q + 1) : r * (q + 1) + (xcd - r) * q) + pos;
  const int bx = wg / nby, by = wg % nby;

  const int wr = wid >> 2, wc = wid & 3;

  f32x4 acc[8][4];
#pragma unroll
  for (int m = 0; m < 8; m++)
#pragma unroll
    for (int n = 0; n < 4; n++) acc[m][n] = f32x4{0.f, 0.f, 0.f, 0.f};

  // staging addressing: dest chunk idx = (wid*2+l)*64 + lane within a half;
  // r=idx>>3, stored chunk s=idx&7 holds logical chunk cc = s ^ (r&7).
  const int idx0 = wid * 128 + lane, idx1 = idx0 + 64;
  const int rS0 = idx0 >> 3, rS1 = idx1 >> 3;
  const int cc0 = (((idx0 & 7) ^ (rS0 & 7)) << 3);
  const int cc1 = (((idx1 & 7) ^ (rS1 & 7)) << 3);
  const ushort* srcA0 = A + ((size_t)by * 256 + rS0) * D + cc0;
  const ushort* srcA1 = A + ((size_t)by * 256 + rS1) * D + cc1;
  const ushort* srcB0 = B + ((size_t)bx * 256 + rS0) * D + cc0;
  const ushort* srcB1 = B + ((size_t)bx * 256 + rS1) * D + cc1;
  const int st0 = wid * 1024, st1 = wid * 1024 + 512;  // ushort offsets in a half

#define STAGE_A(h, tt, bf)                                                      \
  do {                                                                          \
    load_lds16(srcA0 + (size_t)(h)*128 * D + (tt)*64, As + (bf)*16384 + (h)*8192 + st0); \
    load_lds16(srcA1 + (size_t)(h)*128 * D + (tt)*64, As + (bf)*16384 + (h)*8192 + st1); \
  } while (0)
#define STAGE_B(h, tt, bf)                                                      \
  do {                                                                          \
    load_lds16(srcB0 + (size_t)(h)*128 * D + (tt)*64, Bs + (bf)*16384 + (h)*8192 + st0); \
    load_lds16(srcB1 + (size_t)(h)*128 * D + (tt)*64, Bs + (bf)*16384 + (h)*8192 + st1); \
  } while (0)

  // fragment read swizzled chunk offsets (row&7 == l15&7 since m*16 ≡ 0 mod 8)
  const int ck0 = (((0 * 4 + l4) ^ (l15 & 7)) << 3);
  const int ck1 = (((1 * 4 + l4) ^ (l15 & 7)) << 3);
#define LDA(m, kk) (*(const bf16x8*)(abase + (m)*1024 + ((kk) ? ck1 : ck0)))
#define LDB(n, kk) (*(const bf16x8*)(bbase + (n)*1024 + ((kk) ? ck1 : ck0)))
#define MFMA __builtin_amdgcn_mfma_f32_16x16x32_bf16

  // prologue: tile0 all 4 halves + B0(1),A0(1); certify tile0, leave 2 in flight
  STAGE_B(0, 0, 0);
  STAGE_A(0, 0, 0);
  STAGE_B(1, 0, 0);
  STAGE_A(1, 0, 0);
  STAGE_B(0, 1, 1);
  STAGE_A(0, 1, 1);
  asm volatile("s_waitcnt vmcnt(4)" ::: "memory");
  __builtin_amdgcn_s_barrier();

#pragma unroll 1
  for (int kt = 0; kt < 16; ++kt) {
    const int buf = kt & 1, nb = buf ^ 1;
    const ushort* abase = As + buf * 16384 + wr * 8192 + l15 * 64;
    const ushort* bbase = Bs + buf * 16384 + (wc >> 1) * 8192 + ((wc & 1) * 64 + l15) * 64;
    bf16x8 af[4][2], b0[2][2], b2[2][2];

    // ---- p0: read A(m0-3), B(n0-1); stage B1(kt+1); MFMA m0-3 x n0-1
#pragma unroll
    for (int m = 0; m < 4; ++m) { af[m][0] = LDA(m, 0); af[m][1] = LDA(m, 1); }
#pragma unroll
    for (int n = 0; n < 2; ++n) { b0[n][0] = LDB(n, 0); b0[n][1] = LDB(n, 1); }
    if (kt < 15) STAGE_B(1, kt + 1, nb);
    __builtin_amdgcn_s_barrier();
    __builtin_amdgcn_s_setprio(1);
#pragma unroll
    for (int m = 0; m < 4; ++m)
#pragma unroll
      for (int n = 0; n < 2; ++n) {
        acc[m][n] = MFMA(af[m][0], b0[n][0], acc[m][n], 0, 0, 0);
        acc[m][n] = MFMA(af[m][1], b0[n][1], acc[m][n], 0, 0, 0);
      }
    __builtin_amdgcn_s_setprio(0);
    __builtin_amdgcn_s_barrier();

    // ---- p1: read B(n2-3); stage A1(kt+1); MFMA m0-3 x n2-3
#pragma unroll
    for (int n = 0; n < 2; ++n) { b2[n][0] = LDB(n + 2, 0); b2[n][1] = LDB(n + 2, 1); }
    if (kt < 15) STAGE_A(1, kt + 1, nb);
    __builtin_amdgcn_s_barrier();
    __builtin_amdgcn_s_setprio(1);
#pragma unroll
    for (int m = 0; m < 4; ++m)
#pragma unroll
      for (int n = 0; n < 2; ++n) {
        acc[m][n + 2] = MFMA(af[m][0], b2[n][0], acc[m][n + 2], 0, 0, 0);
        acc[m][n + 2] = MFMA(af[m][1], b2[n][1], acc[m][n + 2], 0, 0, 0);
      }
    __builtin_amdgcn_s_setprio(0);
    __builtin_amdgcn_s_barrier();

    // ---- p2: read A(m4-7); stage B0(kt+2); MFMA m4-7 x n2-3
#pragma unroll
    for (int m = 0; m < 4; ++m) { af[m][0] = LDA(m + 4, 0); af[m][1] = LDA(m + 4, 1); }
    if (kt < 14) STAGE_B(0, kt + 2, buf);
    __builtin_amdgcn_s_barrier();
    __builtin_amdgcn_s_setprio(1);
#pragma unroll
    for (int m = 0; m < 4; ++m)
#pragma unroll
      for (int n = 0; n < 2; ++n) {
        acc[m + 4][n + 2] = MFMA(af[m][0], b2[n][0], acc[m + 4][n + 2], 0, 0, 0);
        acc[m + 4][n + 2] = MFMA(af[m][1], b2[n][1], acc[m + 4][n + 2], 0, 0, 0);
      }
    __builtin_amdgcn_s_setprio(0);
    __builtin_amdgcn_s_barrier();

    // ---- p3: no reads; stage A0(kt+2); MFMA m4-7 x n0-1; counted vmcnt
    if (kt < 14) STAGE_A(0, kt + 2, buf);
    __builtin_amdgcn_s_barrier();
    __builtin_amdgcn_s_setprio(1);
#pragma unroll
    for (int m = 0; m < 4; ++m)
#pragma unroll
      for (int n = 0; n < 2; ++n) {
        acc[m + 4][n] = MFMA(af[m][0], b0[n][0], acc[m + 4][n], 0, 0, 0);
        acc[m + 4][n] = MFMA(af[m][1], b0[n][1], acc[m + 4][n], 0, 0, 0);
      }
    __builtin_amdgcn_s_setprio(0);
    if (kt < 14) asm volatile("s_waitcnt vmcnt(4)" ::: "memory");
    else if (kt == 14) asm volatile("s_waitcnt vmcnt(0)" ::: "memory");
    __builtin_amdgcn_s_barrier();
  }
#undef STAGE_A
#undef STAGE_B
#undef LDA
#undef LDB
#undef MFMA

  // epilogue 1: per-row max over 256 cols, atomic-free
#pragma unroll
  for (int m = 0; m < 8; ++m)
#pragma unroll
    for (int j = 0; j < 4; ++j) {
      float fm = fmaxf(fmaxf(acc[m][0][j], acc[m][1][j]), fmaxf(acc[m][2][j], acc[m][3][j]));
#pragma unroll
      for (int off = 1; off < 16; off <<= 1) fm = fmaxf(fm, __shfl_xor(fm, off, 64));
      if (l15 == 0) wmax[wc][wr * 128 + l4 * 4 + m * 16 + j] = fm;
    }
  __syncthreads();
  if (tid < 256) {
    const float fm = fmaxf(fmaxf(wmax[0][tid], wmax[1][tid]), fmaxf(wmax[2][tid], wmax[3][tid]));
    TM[(size_t)bx * srows + by * 256 + tid] = (ushort)key16((unsigned)f2bf(fm));
  }

  // epilogue 2: C-write. layout: row = l4*4 + j, col = l15
  const size_t crow = (size_t)by * 256 + wr * 128 + (l4 << 2);
  const size_t ccol = (size_t)bx * 256 + wc * 64 + l15;
#pragma unroll
  for (int m = 0; m < 8; m++)
#pragma unroll
    for (int n = 0; n < 4; n++)
#pragma unroll
      for (int j = 0; j < 4; j++)
        C[(crow + m * 16 + j) * (size_t)NM + ccol + n * 16] = f2bf(acc[m][n][j]);
}

// ---------- top-32 with tile-max prefilter ----------
#define CAP2 1024
__global__ __launch_bounds__(512) void topk_k(const ushort* __restrict__ scores,
                                              const ushort* __restrict__ tmax,
                                              int srows, int row_base,
                                              const float* __restrict__ temp,
                                              float* __restrict__ attn,
                                              int* __restrict__ idx_out) {
  const int lrow = blockIdx.x;
  const int grow = row_base + lrow;
  const int tid = threadIdx.x;
  const int lane = tid & 63, wid = tid >> 6;
  __shared__ unsigned tlb_s, M_s;
  __shared__ int nqt_s, cnt_s;
  __shared__ ushort qt[NBX];
  __shared__ unsigned ckey[CAP2];
  __shared__ unsigned cand64[64];
  __shared__ unsigned okey[TOPK];
  __shared__ int oidx[TOPK];

  if (tid == 0) cnt_s = 0;

  if (tid < 64) {
    const unsigned ka = tmax[(size_t)lane * srows + lrow];
    const unsigned kb = tmax[(size_t)(lane + 64) * srows + lrow];
    unsigned mx = max(ka, kb);
#pragma unroll
    for (int off = 32; off; off >>= 1) mx = max(mx, __shfl_xor(mx, off, 64));
    unsigned lo = 0, hi = mx;
    while (lo < hi) {
      const unsigned mid = (lo + hi + 1) >> 1;
      int c = (int)(ka >= mid) + (int)(kb >= mid);
#pragma unroll
      for (int off = 32; off; off >>= 1) c += __shfl_xor(c, off, 64);
      if (c >= TOPK) lo = mid; else hi = mid - 1;
    }
    const bool pa = ka >= lo;
    unsigned long long bm = __ballot(pa);
    if (pa) qt[__popcll(bm & ((1ull << lane) - 1ull))] = (ushort)lane;
    int base = __popcll(bm);
    const bool pb = kb >= lo;
    bm = __ballot(pb);
    if (pb) qt[base + __popcll(bm & ((1ull << lane) - 1ull))] = (ushort)(lane + 64);
    base += __popcll(bm);
    if (lane == 0) { nqt_s = base; tlb_s = lo; M_s = mx; }
  }
  __syncthreads();
  const unsigned M = M_s;
  const int nqt = nqt_s;
  unsigned t0 = tlb_s;
  unsigned tlo = t0, thi = M;

  const unsigned* rowu = (const unsigned*)(scores + (size_t)lrow * NM);
  int cnt = 0;
  for (int att = 0; att < 18; ++att) {
    for (int i = wid; i < nqt; i += 8) {
      const int tb = qt[i];
#pragma unroll
      for (int p = 0; p < 2; ++p) {
        const unsigned u = rowu[tb * 128 + lane * 2 + p];
        const unsigned m = (u >> 15) & 0x00010001u;
        const unsigned kk = u ^ (m * 0x7FFFu + 0x80008000u);
        const unsigned klo = kk & 0xFFFFu, khi = kk >> 16;
        const int bidx = tb * 256 + (lane * 2 + p) * 2;
        if (klo >= t0) { const int qq = atomicAdd(&cnt_s, 1); if (qq < CAP2) ckey[qq] = (klo << 16) | (unsigned)(32767 - bidx); }
        if (khi >= t0) { const int qq = atomicAdd(&cnt_s, 1); if (qq < CAP2) ckey[qq] = (khi << 16) | (unsigned)(32767 - (bidx + 1)); }
      }
    }
    __syncthreads();
    cnt = cnt_s;
    __syncthreads();
    if ((cnt >= TOPK && cnt <= CAP2) || att == 17) break;
    if (cnt > CAP2) { tlo = t0; t0 = t0 + ((thi - t0 + 1) >> 1); }
    else { thi = t0; t0 = tlo + ((t0 - tlo) >> 1); }
    if (tid == 0) cnt_s = 0;
    __syncthreads();
  }
  const int n = min(cnt, CAP2);

  if (tid < 64) {
    unsigned lo = t0, hi = M;
    while (lo < hi) {
      const unsigned mid = (lo + hi + 1) >> 1;
      int c = 0;
      for (int i = lane; i < n; i += 64) c += (int)((ckey[i] >> 16) >= mid);
#pragma unroll
      for (int off = 32; off; off >>= 1) c += __shfl_xor(c, off, 64);
      if (c >= TOPK) lo = mid; else hi = mid - 1;
    }
    const unsigned t32 = lo;
    int c32 = 0;
    for (int i = lane; i < n; i += 64) c32 += (int)((ckey[i] >> 16) >= t32);
#pragma unroll
    for (int off = 32; off; off >>= 1) c32 += __shfl_xor(c32, off, 64);

    if (c32 <= 64) {
      cand64[lane] = 0;
      int base = 0;
      for (int r0 = 0; r0 < n; r0 += 64) {
        const int i = r0 + lane;
        const unsigned k = (i < n) ? ckey[i] : 0u;
        const bool p = (k >> 16) >= t32;
        const unsigned long long bm = __ballot(p);
        if (p) {
          const int ps = base + __popcll(bm & ((1ull << lane) - 1ull));
          if (ps < 64) cand64[ps] = k;
        }
        base += __popcll(bm);
      }
      unsigned v = cand64[lane];
#pragma unroll
      for (int k2 = 2; k2 <= 64; k2 <<= 1) {
#pragma unroll
        for (int j = k2 >> 1; j > 0; j >>= 1) {
          const unsigned o = __shfl_xor(v, j, 64);
          const bool lower = (lane & j) == 0;
          const bool descB = (lane & k2) == 0;
          const unsigned mxv = v > o ? v : o;
          const unsigned mnv = v > o ? o : v;
          v = (lower == descB) ? mxv : mnv;
        }
      }
      if (lane < TOPK) {
        okey[lane] = v >> 16;
        oidx[lane] = 32767 - (int)(v & 0x7FFFu);
      }
    } else {
      for (int k = 0; k < TOPK; ++k) {
        unsigned bk = 0;
        for (int j = lane; j < n; j += 64) bk = max(bk, ckey[j]);
#pragma unroll
        for (int off = 32; off; off >>= 1) bk = max(bk, __shfl_xor(bk, off, 64));
        if (lane == 0) {
          okey[k] = bk >> 16;
          oidx[k] = 32767 - (int)(bk & 0x7FFFu);
        }
        for (int j = lane; j < n; j += 64)
          if (ckey[j] == bk) ckey[j] = 0;
      }
    }
  }
  __syncthreads();

  if (tid < TOPK) {
    const float T = fabsf(temp[0]);
    const unsigned k0 = okey[tid];
    const unsigned u0 = (k0 & 0x8000u) ? (k0 ^ 0x8000u) : (k0 ^ 0xFFFFu);
    const unsigned km = okey[0];
    const unsigned um = (km & 0x8000u) ? (km ^ 0x8000u) : (km ^ 0xFFFFu);
    const float s = __uint_as_float(u0 << 16) * T;
    const float mx = __uint_as_float(um << 16) * T;
    const float e = __expf(s - mx);
    float sum = e;
#pragma unroll
    for (int off = 16; off; off >>= 1) sum += __shfl_xor(sum, off, 32);
    attn[(size_t)grow * TOPK + tid] = e / sum;
    idx_out[(size_t)grow * TOPK + tid] = oidx[tid];
  }
}

// ---------- gather values + residual + LayerNorm ----------
__global__ __launch_bounds__(256) void gather_ln_k(const float* __restrict__ V,
                                                   const float* __restrict__ Q,
                                                   const float* __restrict__ gamma,
                                                   const float* __restrict__ beta,
                                                   const float* __restrict__ attn,
                                                   const int* __restrict__ idx,
                                                   float* __restrict__ out) {
  const int row = blockIdx.x, tid = threadIdx.x;
  __shared__ float a_s[TOPK];
  __shared__ int i_s[TOPK];
  __shared__ float redS[4], redQ[4];
  if (tid < TOPK) {
    a_s[tid] = attn[(size_t)row * TOPK + tid];
    i_s[tid] = idx[(size_t)row * TOPK + tid];
  }
  __syncthreads();
  float4 acc = {0.f, 0.f, 0.f, 0.f};
#pragma unroll
  for (int kb = 0; kb < TOPK; kb += 8) {
    float4 v[8];
#pragma unroll
    for (int u = 0; u < 8; ++u)
      v[u] = ((const float4*)(V + (size_t)i_s[kb + u] * D))[tid];
#pragma unroll
    for (int u = 0; u < 8; ++u) {
      const float a = a_s[kb + u];
      acc.x = fmaf(a, v[u].x, acc.x);
      acc.y = fmaf(a, v[u].y, acc.y);
      acc.z = fmaf(a, v[u].z, acc.z);
      acc.w = fmaf(a, v[u].w, acc.w);
    }
  }
  const float4 q = ((const float4*)(Q + (size_t)row * D))[tid];
  float4 x = {acc.x + q.x, acc.y + q.y, acc.z + q.z, acc.w + q.w};
  float s = x.x + x.y + x.z + x.w;
  float ss = x.x * x.x + x.y * x.y + x.z * x.z + x.w * x.w;
#pragma unroll
  for (int off = 32; off; off >>= 1) {
    s += __shfl_xor(s, off, 64);
    ss += __shfl_xor(ss, off, 64);
  }
  const int wid = tid >> 6, lane = tid & 63;
  if (lane == 0) { redS[wid] = s; redQ[wid] = ss; }
  __syncthreads();
  const float S = redS[0] + redS[1] + redS[2] + redS[3];
  const float SS = redQ[0] + redQ[1] + redQ[2] + redQ[3];
  const float mu = S * (1.0f / D);
  const float var = SS * (1.0f / D) - mu * mu;
  const float rstd = rsqrtf(var + 1e-5f);
  const float4 g = ((const float4*)gamma)[tid];
  const float4 b = ((const float4*)beta)[tid];
  float4 o;
  o.x = (x.x - mu) * rstd * g.x + b.x;
  o.y = (x.y - mu) * rstd * g.y + b.y;
  o.z = (x.z - mu) * rstd * g.z + b.z;
  o.w = (x.w - mu) * rstd * g.w + b.w;
  ((float4*)(out + (size_t)row * D))[tid] = o;
}

extern "C" void kernel_launch(void* const* d_in, const int* in_sizes, int n_in,
                              void* d_out, int out_size, void* d_ws, size_t ws_size,
                              hipStream_t stream) {
  const float* Q = (const float*)d_in[0];
  const float* K = (const float*)d_in[1];
  const float* V = (const float*)d_in[2];
  const float* T = (const float*)d_in[3];
  const float* G = (const float*)d_in[4];
  const float* Bt = (const float*)d_in[5];
  float* out = (float*)d_out;
  float* attn = out + (size_t)NQ * D;

  char* ws = (char*)d_ws;
  const size_t off_qn = 0;
  const size_t off_kn = off_qn + (size_t)NQ * D * 2;
  const size_t off_idx = off_kn + (size_t)NM * D * 2;
  const size_t off_tm = off_idx + (size_t)NQ * TOPK * sizeof(int);
  const size_t off_sc = off_tm + (size_t)NBX * 2048 * 2;
  ushort* qn = (ushort*)(ws + off_qn);
  ushort* kn = (ushort*)(ws + off_kn);
  int* idx = (int*)(ws + off_idx);
  ushort* tm = (ushort*)(ws + off_tm);
  ushort* scores = (ushort*)(ws + off_sc);

  const size_t avail = ws_size > off_sc ? ws_size - off_sc : 0;
  int slice = 2048;
  while (slice > 256 && (size_t)slice * NM * 2ull > avail) slice >>= 1;

  norm_cast_k<<<NQ, 256, 0, stream>>>(Q, qn);
  norm_cast_k<<<NM, 256, 0, stream>>>(K, kn);

  const int nbx = NM / 256;
  for (int s0 = 0; s0 < NQ; s0 += slice) {
    const int nby = slice / 256;
    gemm256<<<nbx * nby, 512, 0, stream>>>(qn + (size_t)s0 * D, kn, scores, tm, nby, slice);
    topk_k<<<slice, 512, 0, stream>>>(scores, tm, slice, s0, T, attn, idx);
  }
  gather_ln_k<<<NQ, 256, 0, stream>>>(V, Q, G, Bt, attn, idx, out);
}

// Round 9
// 903.590 us; speedup vs baseline: 1.5317x; 1.0763x over previous
//
#include <hip/hip_runtime.h>
#include <hip/hip_bf16.h>

#define D 1024
#define NQ 8192
#define NM 32768
#define TOPK 32
#define NBXT 256  // 128-col tiles per row

typedef __attribute__((ext_vector_type(8))) __bf16 bf16x8;
typedef __attribute__((ext_vector_type(4))) float f32x4;

__device__ __forceinline__ void load_lds16(const void* g, void* l) {
  __builtin_amdgcn_global_load_lds(
      (const __attribute__((address_space(1))) void*)g,
      (__attribute__((address_space(3))) void*)l, 16, 0, 0);
}

__device__ __forceinline__ ushort f2bf(float f) {
  unsigned u = __float_as_uint(f);
  unsigned r = (u + 0x7FFFu + ((u >> 16) & 1u)) >> 16;
  return (ushort)r;
}
__device__ __forceinline__ unsigned key16(unsigned u) {
  return u ^ ((u & 0x8000u) ? 0xFFFFu : 0x8000u);
}

// ---------- row L2-normalize f32 -> bf16 ----------
__global__ __launch_bounds__(256) void norm_cast_k(const float* __restrict__ in,
                                                   ushort* __restrict__ out) {
  const int row = blockIdx.x;
  const int tid = threadIdx.x;
  const float4 v = ((const float4*)(in + (size_t)row * D))[tid];
  float ss = v.x * v.x + v.y * v.y + v.z * v.z + v.w * v.w;
#pragma unroll
  for (int off = 32; off; off >>= 1) ss += __shfl_xor(ss, off, 64);
  __shared__ float wsum[4];
  const int wid = tid >> 6, lane = tid & 63;
  if (lane == 0) wsum[wid] = ss;
  __syncthreads();
  const float tot = wsum[0] + wsum[1] + wsum[2] + wsum[3];
  const float inv = 1.0f / fmaxf(sqrtf(tot), 1e-12f);
  ushort4 o;
  o.x = f2bf(v.x * inv);
  o.y = f2bf(v.y * inv);
  o.z = f2bf(v.z * inv);
  o.w = f2bf(v.w * inv);
  ((ushort4*)(out + (size_t)row * D))[tid] = o;
}

// ---------- 128x128 bf16 GEMM, BK=64 single-buffer, 4 blocks/CU ----------
// m97 structure: stage -> sync -> frags+MFMA -> sync. Cross-block wave overlap
// (4 co-resident blocks) hides staging latency; no hand-rolled sync.
// LDS 33KB: As[128][64] + Bs[128][64] (XOR-8 chunk swizzle), C-stage aliases both.
__global__ __launch_bounds__(256, 4) void gemm128(const ushort* __restrict__ A,
                                                  const ushort* __restrict__ B,
                                                  ushort* __restrict__ C,
                                                  ushort* __restrict__ TM,
                                                  int nby, int srows) {
  __shared__ alignas(16) ushort lds[16384];  // As[0:8192] Bs[8192:16384]; C-stage alias
  __shared__ float wmax[2][128];
  ushort* const As = lds;
  ushort* const Bs = lds + 8192;
  const int tid = threadIdx.x;
  const int lane = tid & 63, wid = tid >> 6;
  const int l15 = lane & 15, l4 = lane >> 4;

  // T1: bijective XCD swizzle
  const int nwg = (int)gridDim.x;
  const int q = nwg >> 3, r = nwg & 7;
  const int xcd = (int)blockIdx.x & 7, pos = (int)blockIdx.x >> 3;
  const int wg = (xcd < r ? xcd * (q + 1) : r * (q + 1) + (xcd - r) * q) + pos;
  const int bx = wg / nby, by = wg % nby;

  const int wr = wid >> 1, wc = wid & 1;  // 2x2 waves, each 64x64 of C

  f32x4 acc[4][4];
#pragma unroll
  for (int m = 0; m < 4; m++)
#pragma unroll
    for (int n = 0; n < 4; n++) acc[m][n] = f32x4{0.f, 0.f, 0.f, 0.f};

  // staging: 1024 chunks(16B)/operand/tile; thread t covers ci = wid*64+l*256+lane.
  // stored chunk sc=ci&7 holds logical chunk lc = sc ^ (row&7) (pre-swizzled source).
  const int swz = ((lane & 7) ^ (lane >> 3)) << 3;  // elements
  const ushort* gA = A + ((size_t)by * 128 + wid * 8 + (lane >> 3)) * D + swz;
  const ushort* gB = B + ((size_t)bx * 128 + wid * 8 + (lane >> 3)) * D + swz;
  ushort* const ldsA = As + wid * 64 * 8;
  ushort* const ldsB = Bs + wid * 64 * 8;

#pragma unroll 1
  for (int kt = 0; kt < 16; ++kt) {
    const int ko = kt * 64;
#pragma unroll
    for (int l = 0; l < 4; ++l) {
      load_lds16(gA + (size_t)l * 32 * D + ko, ldsA + l * 2048);
      load_lds16(gB + (size_t)l * 32 * D + ko, ldsB + l * 2048);
    }
    __syncthreads();
#pragma unroll
    for (int h = 0; h < 2; ++h) {
      bf16x8 af[4], bfv[4];
      const int ck = ((h * 4 + l4) ^ (l15 & 7)) << 3;
#pragma unroll
      for (int m = 0; m < 4; ++m)
        af[m] = *(const bf16x8*)&As[(wr * 64 + m * 16 + l15) * 64 + ck];
#pragma unroll
      for (int n = 0; n < 4; ++n)
        bfv[n] = *(const bf16x8*)&Bs[(wc * 64 + n * 16 + l15) * 64 + ck];
#pragma unroll
      for (int m = 0; m < 4; ++m)
#pragma unroll
        for (int n = 0; n < 4; ++n)
          acc[m][n] = __builtin_amdgcn_mfma_f32_16x16x32_bf16(af[m], bfv[n], acc[m][n], 0, 0, 0);
    }
    __syncthreads();
  }

  // epilogue 1: per-row max over this block's 128 cols (atomic-free)
#pragma unroll
  for (int m = 0; m < 4; ++m)
#pragma unroll
    for (int j = 0; j < 4; ++j) {
      float fm = fmaxf(fmaxf(acc[m][0][j], acc[m][1][j]), fmaxf(acc[m][2][j], acc[m][3][j]));
#pragma unroll
      for (int off = 1; off < 16; off <<= 1) fm = fmaxf(fm, __shfl_xor(fm, off, 64));
      if (l15 == 0) wmax[wc][wr * 64 + l4 * 4 + m * 16 + j] = fm;
    }
  __syncthreads();
  if (tid < 128) {
    const float fm = fmaxf(wmax[0][tid], wmax[1][tid]);
    TM[(size_t)bx * srows + by * 128 + tid] = (ushort)key16((unsigned)f2bf(fm));
  }

  // epilogue 2: stage C-tile to LDS (chunk-XOR swizzle), stream out coalesced.
  // C/D frag layout: row = l4*4 + j (+m*16, +wr*64), col = l15 (+n*16, +wc*64).
#pragma unroll
  for (int m = 0; m < 4; ++m)
#pragma unroll
    for (int n = 0; n < 4; ++n) {
      const int col = wc * 64 + n * 16 + l15;
      const int c8 = col >> 3, c7 = col & 7;
#pragma unroll
      for (int j = 0; j < 4; ++j) {
        const int row = wr * 64 + m * 16 + l4 * 4 + j;
        lds[row * 128 + ((c8 ^ (row & 7)) << 3) + c7] = f2bf(acc[m][n][j]);
      }
    }
  __syncthreads();
  const int orow = tid >> 4, seg = tid & 15;
#pragma unroll
  for (int p = 0; p < 8; ++p) {
    const int row = p * 16 + orow;
    const bf16x8 v = *(const bf16x8*)&lds[row * 128 + ((seg ^ (row & 7)) << 3)];
    *(bf16x8*)&C[((size_t)by * 128 + row) * NM + bx * 128 + seg * 8] = v;
  }
}

// ---------- top-32 with 128-col tile-max prefilter ----------
#define CAP2 1024
__global__ __launch_bounds__(512) void topk_k(const ushort* __restrict__ scores,
                                              const ushort* __restrict__ tmax,
                                              int srows, int row_base,
                                              const float* __restrict__ temp,
                                              float* __restrict__ attn,
                                              int* __restrict__ idx_out) {
  const int lrow = blockIdx.x;
  const int grow = row_base + lrow;
  const int tid = threadIdx.x;
  const int lane = tid & 63, wid = tid >> 6;
  __shared__ unsigned tlb_s, M_s;
  __shared__ int nqt_s, cnt_s;
  __shared__ ushort qt[NBXT];
  __shared__ unsigned ckey[CAP2];
  __shared__ unsigned cand64[64];
  __shared__ unsigned okey[TOPK];
  __shared__ int oidx[TOPK];

  if (tid == 0) cnt_s = 0;

  // step 1 (wave 0): 32nd-largest of 256 tile-maxes -> sound lower bound t_lb
  if (tid < 64) {
    const unsigned k0 = tmax[(size_t)lane * srows + lrow];
    const unsigned k1 = tmax[(size_t)(lane + 64) * srows + lrow];
    const unsigned k2 = tmax[(size_t)(lane + 128) * srows + lrow];
    const unsigned k3 = tmax[(size_t)(lane + 192) * srows + lrow];
    unsigned mx = max(max(k0, k1), max(k2, k3));
#pragma unroll
    for (int off = 32; off; off >>= 1) mx = max(mx, __shfl_xor(mx, off, 64));
    unsigned lo = 0, hi = mx;
    while (lo < hi) {
      const unsigned mid = (lo + hi + 1) >> 1;
      int c = (int)(k0 >= mid) + (int)(k1 >= mid) + (int)(k2 >= mid) + (int)(k3 >= mid);
#pragma unroll
      for (int off = 32; off; off >>= 1) c += __shfl_xor(c, off, 64);
      if (c >= TOPK) lo = mid; else hi = mid - 1;
    }
    int base = 0;
    {
      const bool p = k0 >= lo;
      const unsigned long long bm = __ballot(p);
      if (p) qt[base + __popcll(bm & ((1ull << lane) - 1ull))] = (ushort)lane;
      base += __popcll(bm);
    }
    {
      const bool p = k1 >= lo;
      const unsigned long long bm = __ballot(p);
      if (p) qt[base + __popcll(bm & ((1ull << lane) - 1ull))] = (ushort)(lane + 64);
      base += __popcll(bm);
    }
    {
      const bool p = k2 >= lo;
      const unsigned long long bm = __ballot(p);
      if (p) qt[base + __popcll(bm & ((1ull << lane) - 1ull))] = (ushort)(lane + 128);
      base += __popcll(bm);
    }
    {
      const bool p = k3 >= lo;
      const unsigned long long bm = __ballot(p);
      if (p) qt[base + __popcll(bm & ((1ull << lane) - 1ull))] = (ushort)(lane + 192);
      base += __popcll(bm);
    }
    if (lane == 0) { nqt_s = base; tlb_s = lo; M_s = mx; }
  }
  __syncthreads();
  const unsigned M = M_s;
  const int nqt = nqt_s;
  unsigned t0 = tlb_s;
  unsigned tlo = t0, thi = M;

  // step 2: collect candidates >= t0 from qualifying 128-col tiles only
  const unsigned* rowu = (const unsigned*)(scores + (size_t)lrow * NM);
  int cnt = 0;
  for (int att = 0; att < 18; ++att) {
    for (int i = wid; i < nqt; i += 8) {
      const int tb = qt[i];
      const unsigned u = rowu[tb * 64 + lane];
      const unsigned m = (u >> 15) & 0x00010001u;
      const unsigned kk = u ^ (m * 0x7FFFu + 0x80008000u);
      const unsigned klo = kk & 0xFFFFu, khi = kk >> 16;
      const int bidx = tb * 128 + lane * 2;
      if (klo >= t0) { const int qq = atomicAdd(&cnt_s, 1); if (qq < CAP2) ckey[qq] = (klo << 16) | (unsigned)(32767 - bidx); }
      if (khi >= t0) { const int qq = atomicAdd(&cnt_s, 1); if (qq < CAP2) ckey[qq] = (khi << 16) | (unsigned)(32767 - (bidx + 1)); }
    }
    __syncthreads();
    cnt = cnt_s;
    __syncthreads();
    if ((cnt >= TOPK && cnt <= CAP2) || att == 17) break;
    if (cnt > CAP2) { tlo = t0; t0 = t0 + ((thi - t0 + 1) >> 1); }
    else { thi = t0; t0 = tlo + ((t0 - tlo) >> 1); }
    if (tid == 0) cnt_s = 0;
    __syncthreads();
  }
  const int n = min(cnt, CAP2);

  // step 3 (wave 0): exact 32nd, compact, bitonic sort, softmax
  if (tid < 64) {
    unsigned lo = t0, hi = M;
    while (lo < hi) {
      const unsigned mid = (lo + hi + 1) >> 1;
      int c = 0;
      for (int i = lane; i < n; i += 64) c += (int)((ckey[i] >> 16) >= mid);
#pragma unroll
      for (int off = 32; off; off >>= 1) c += __shfl_xor(c, off, 64);
      if (c >= TOPK) lo = mid; else hi = mid - 1;
    }
    const unsigned t32 = lo;
    int c32 = 0;
    for (int i = lane; i < n; i += 64) c32 += (int)((ckey[i] >> 16) >= t32);
#pragma unroll
    for (int off = 32; off; off >>= 1) c32 += __shfl_xor(c32, off, 64);

    if (c32 <= 64) {
      cand64[lane] = 0;
      int base = 0;
      for (int r0 = 0; r0 < n; r0 += 64) {
        const int i = r0 + lane;
        const unsigned k = (i < n) ? ckey[i] : 0u;
        const bool p = (k >> 16) >= t32;
        const unsigned long long bm = __ballot(p);
        if (p) {
          const int ps = base + __popcll(bm & ((1ull << lane) - 1ull));
          if (ps < 64) cand64[ps] = k;
        }
        base += __popcll(bm);
      }
      unsigned v = cand64[lane];
#pragma unroll
      for (int k2 = 2; k2 <= 64; k2 <<= 1) {
#pragma unroll
        for (int j = k2 >> 1; j > 0; j >>= 1) {
          const unsigned o = __shfl_xor(v, j, 64);
          const bool lower = (lane & j) == 0;
          const bool descB = (lane & k2) == 0;
          const unsigned mxv = v > o ? v : o;
          const unsigned mnv = v > o ? o : v;
          v = (lower == descB) ? mxv : mnv;
        }
      }
      if (lane < TOPK) {
        okey[lane] = v >> 16;
        oidx[lane] = 32767 - (int)(v & 0x7FFFu);
      }
    } else {
      for (int k = 0; k < TOPK; ++k) {
        unsigned bk = 0;
        for (int j = lane; j < n; j += 64) bk = max(bk, ckey[j]);
#pragma unroll
        for (int off = 32; off; off >>= 1) bk = max(bk, __shfl_xor(bk, off, 64));
        if (lane == 0) {
          okey[k] = bk >> 16;
          oidx[k] = 32767 - (int)(bk & 0x7FFFu);
        }
        for (int j = lane; j < n; j += 64)
          if (ckey[j] == bk) ckey[j] = 0;
      }
    }
  }
  __syncthreads();

  if (tid < TOPK) {
    const float T = fabsf(temp[0]);
    const unsigned k0 = okey[tid];
    const unsigned u0 = (k0 & 0x8000u) ? (k0 ^ 0x8000u) : (k0 ^ 0xFFFFu);
    const unsigned km = okey[0];
    const unsigned um = (km & 0x8000u) ? (km ^ 0x8000u) : (km ^ 0xFFFFu);
    const float s = __uint_as_float(u0 << 16) * T;
    const float mx = __uint_as_float(um << 16) * T;
    const float e = __expf(s - mx);
    float sum = e;
#pragma unroll
    for (int off = 16; off; off >>= 1) sum += __shfl_xor(sum, off, 32);
    attn[(size_t)grow * TOPK + tid] = e / sum;
    idx_out[(size_t)grow * TOPK + tid] = oidx[tid];
  }
}

// ---------- gather values + residual + LayerNorm ----------
__global__ __launch_bounds__(256) void gather_ln_k(const float* __restrict__ V,
                                                   const float* __restrict__ Q,
                                                   const float* __restrict__ gamma,
                                                   const float* __restrict__ beta,
                                                   const float* __restrict__ attn,
                                                   const int* __restrict__ idx,
                                                   float* __restrict__ out) {
  const int row = blockIdx.x, tid = threadIdx.x;
  __shared__ float a_s[TOPK];
  __shared__ int i_s[TOPK];
  __shared__ float redS[4], redQ[4];
  if (tid < TOPK) {
    a_s[tid] = attn[(size_t)row * TOPK + tid];
    i_s[tid] = idx[(size_t)row * TOPK + tid];
  }
  __syncthreads();
  float4 acc = {0.f, 0.f, 0.f, 0.f};
#pragma unroll
  for (int kb = 0; kb < TOPK; kb += 8) {
    float4 v[8];
#pragma unroll
    for (int u = 0; u < 8; ++u)
      v[u] = ((const float4*)(V + (size_t)i_s[kb + u] * D))[tid];
#pragma unroll
    for (int u = 0; u < 8; ++u) {
      const float a = a_s[kb + u];
      acc.x = fmaf(a, v[u].x, acc.x);
      acc.y = fmaf(a, v[u].y, acc.y);
      acc.z = fmaf(a, v[u].z, acc.z);
      acc.w = fmaf(a, v[u].w, acc.w);
    }
  }
  const float4 q = ((const float4*)(Q + (size_t)row * D))[tid];
  float4 x = {acc.x + q.x, acc.y + q.y, acc.z + q.z, acc.w + q.w};
  float s = x.x + x.y + x.z + x.w;
  float ss = x.x * x.x + x.y * x.y + x.z * x.z + x.w * x.w;
#pragma unroll
  for (int off = 32; off; off >>= 1) {
    s += __shfl_xor(s, off, 64);
    ss += __shfl_xor(ss, off, 64);
  }
  const int wid = tid >> 6, lane = tid & 63;
  if (lane == 0) { redS[wid] = s; redQ[wid] = ss; }
  __syncthreads();
  const float S = redS[0] + redS[1] + redS[2] + redS[3];
  const float SS = redQ[0] + redQ[1] + redQ[2] + redQ[3];
  const float mu = S * (1.0f / D);
  const float var = SS * (1.0f / D) - mu * mu;
  const float rstd = rsqrtf(var + 1e-5f);
  const float4 g = ((const float4*)gamma)[tid];
  const float4 b = ((const float4*)beta)[tid];
  float4 o;
  o.x = (x.x - mu) * rstd * g.x + b.x;
  o.y = (x.y - mu) * rstd * g.y + b.y;
  o.z = (x.z - mu) * rstd * g.z + b.z;
  o.w = (x.w - mu) * rstd * g.w + b.w;
  ((float4*)(out + (size_t)row * D))[tid] = o;
}

extern "C" void kernel_launch(void* const* d_in, const int* in_sizes, int n_in,
                              void* d_out, int out_size, void* d_ws, size_t ws_size,
                              hipStream_t stream) {
  const float* Q = (const float*)d_in[0];
  const float* K = (const float*)d_in[1];
  const float* V = (const float*)d_in[2];
  const float* T = (const float*)d_in[3];
  const float* G = (const float*)d_in[4];
  const float* Bt = (const float*)d_in[5];
  float* out = (float*)d_out;
  float* attn = out + (size_t)NQ * D;

  char* ws = (char*)d_ws;
  const size_t off_qn = 0;
  const size_t off_kn = off_qn + (size_t)NQ * D * 2;
  const size_t off_idx = off_kn + (size_t)NM * D * 2;
  const size_t off_tm = off_idx + (size_t)NQ * TOPK * sizeof(int);
  const size_t off_sc = off_tm + (size_t)NBXT * 2048 * 2;
  ushort* qn = (ushort*)(ws + off_qn);
  ushort* kn = (ushort*)(ws + off_kn);
  int* idx = (int*)(ws + off_idx);
  ushort* tm = (ushort*)(ws + off_tm);
  ushort* scores = (ushort*)(ws + off_sc);

  const size_t avail = ws_size > off_sc ? ws_size - off_sc : 0;
  int slice = 2048;
  while (slice > 256 && (size_t)slice * NM * 2ull > avail) slice >>= 1;

  norm_cast_k<<<NQ, 256, 0, stream>>>(Q, qn);
  norm_cast_k<<<NM, 256, 0, stream>>>(K, kn);

  const int nbx = NM / 128;
  for (int s0 = 0; s0 < NQ; s0 += slice) {
    const int nby = slice / 128;
    gemm128<<<nbx * nby, 256, 0, stream>>>(qn + (size_t)s0 * D, kn, scores, tm, nby, slice);
    topk_k<<<slice, 512, 0, stream>>>(scores, tm, slice, s0, T, attn, idx);
  }
  gather_ln_k<<<NQ, 256, 0, stream>>>(V, Q, G, Bt, attn, idx, out);
}

// Round 10
// 865.529 us; speedup vs baseline: 1.5990x; 1.0440x over previous
//
#include <hip/hip_runtime.h>
#include <hip/hip_bf16.h>

#define D 1024
#define NQ 8192
#define NM 32768
#define TOPK 32
#define NBXT 256  // 128-col tiles per row

typedef __attribute__((ext_vector_type(8))) __bf16 bf16x8;
typedef __attribute__((ext_vector_type(4))) float f32x4;

__device__ __forceinline__ void load_lds16(const void* g, void* l) {
  __builtin_amdgcn_global_load_lds(
      (const __attribute__((address_space(1))) void*)g,
      (__attribute__((address_space(3))) void*)l, 16, 0, 0);
}

__device__ __forceinline__ ushort f2bf(float f) {
  unsigned u = __float_as_uint(f);
  unsigned r = (u + 0x7FFFu + ((u >> 16) & 1u)) >> 16;
  return (ushort)r;
}
__device__ __forceinline__ unsigned key16(unsigned u) {
  return u ^ ((u & 0x8000u) ? 0xFFFFu : 0x8000u);
}
__device__ __forceinline__ float bf2f(ushort u) {
  return __uint_as_float(((unsigned)u) << 16);
}

// ---------- row L2-normalize f32 -> bf16 ----------
__global__ __launch_bounds__(256) void norm_cast_k(const float* __restrict__ in,
                                                   ushort* __restrict__ out) {
  const int row = blockIdx.x;
  const int tid = threadIdx.x;
  const float4 v = ((const float4*)(in + (size_t)row * D))[tid];
  float ss = v.x * v.x + v.y * v.y + v.z * v.z + v.w * v.w;
#pragma unroll
  for (int off = 32; off; off >>= 1) ss += __shfl_xor(ss, off, 64);
  __shared__ float wsum[4];
  const int wid = tid >> 6, lane = tid & 63;
  if (lane == 0) wsum[wid] = ss;
  __syncthreads();
  const float tot = wsum[0] + wsum[1] + wsum[2] + wsum[3];
  const float inv = 1.0f / fmaxf(sqrtf(tot), 1e-12f);
  ushort4 o;
  o.x = f2bf(v.x * inv);
  o.y = f2bf(v.y * inv);
  o.z = f2bf(v.z * inv);
  o.w = f2bf(v.w * inv);
  ((ushort4*)(out + (size_t)row * D))[tid] = o;
}

// ---------- plain f32 -> bf16 cast (V table) ----------
__global__ __launch_bounds__(256) void cast_v_k(const float* __restrict__ in,
                                                ushort* __restrict__ out) {
  const int row = blockIdx.x;
  const int tid = threadIdx.x;
  const float4 v = ((const float4*)(in + (size_t)row * D))[tid];
  ushort4 o;
  o.x = f2bf(v.x);
  o.y = f2bf(v.y);
  o.z = f2bf(v.z);
  o.w = f2bf(v.w);
  ((ushort4*)(out + (size_t)row * D))[tid] = o;
}

// ---------- 128x128 bf16 GEMM, BK=64 single-buffer, 4 blocks/CU (R9, unchanged) ----------
__global__ __launch_bounds__(256, 4) void gemm128(const ushort* __restrict__ A,
                                                  const ushort* __restrict__ B,
                                                  ushort* __restrict__ C,
                                                  ushort* __restrict__ TM,
                                                  int nby, int srows) {
  __shared__ alignas(16) ushort lds[16384];
  __shared__ float wmax[2][128];
  ushort* const As = lds;
  ushort* const Bs = lds + 8192;
  const int tid = threadIdx.x;
  const int lane = tid & 63, wid = tid >> 6;
  const int l15 = lane & 15, l4 = lane >> 4;

  const int nwg = (int)gridDim.x;
  const int q = nwg >> 3, r = nwg & 7;
  const int xcd = (int)blockIdx.x & 7, pos = (int)blockIdx.x >> 3;
  const int wg = (xcd < r ? xcd * (q + 1) : r * (q + 1) + (xcd - r) * q) + pos;
  const int bx = wg / nby, by = wg % nby;

  const int wr = wid >> 1, wc = wid & 1;

  f32x4 acc[4][4];
#pragma unroll
  for (int m = 0; m < 4; m++)
#pragma unroll
    for (int n = 0; n < 4; n++) acc[m][n] = f32x4{0.f, 0.f, 0.f, 0.f};

  const int swz = ((lane & 7) ^ (lane >> 3)) << 3;
  const ushort* gA = A + ((size_t)by * 128 + wid * 8 + (lane >> 3)) * D + swz;
  const ushort* gB = B + ((size_t)bx * 128 + wid * 8 + (lane >> 3)) * D + swz;
  ushort* const ldsA = As + wid * 64 * 8;
  ushort* const ldsB = Bs + wid * 64 * 8;

#pragma unroll 1
  for (int kt = 0; kt < 16; ++kt) {
    const int ko = kt * 64;
#pragma unroll
    for (int l = 0; l < 4; ++l) {
      load_lds16(gA + (size_t)l * 32 * D + ko, ldsA + l * 2048);
      load_lds16(gB + (size_t)l * 32 * D + ko, ldsB + l * 2048);
    }
    __syncthreads();
#pragma unroll
    for (int h = 0; h < 2; ++h) {
      bf16x8 af[4], bfv[4];
      const int ck = ((h * 4 + l4) ^ (l15 & 7)) << 3;
#pragma unroll
      for (int m = 0; m < 4; ++m)
        af[m] = *(const bf16x8*)&As[(wr * 64 + m * 16 + l15) * 64 + ck];
#pragma unroll
      for (int n = 0; n < 4; ++n)
        bfv[n] = *(const bf16x8*)&Bs[(wc * 64 + n * 16 + l15) * 64 + ck];
#pragma unroll
      for (int m = 0; m < 4; ++m)
#pragma unroll
        for (int n = 0; n < 4; ++n)
          acc[m][n] = __builtin_amdgcn_mfma_f32_16x16x32_bf16(af[m], bfv[n], acc[m][n], 0, 0, 0);
    }
    __syncthreads();
  }

#pragma unroll
  for (int m = 0; m < 4; ++m)
#pragma unroll
    for (int j = 0; j < 4; ++j) {
      float fm = fmaxf(fmaxf(acc[m][0][j], acc[m][1][j]), fmaxf(acc[m][2][j], acc[m][3][j]));
#pragma unroll
      for (int off = 1; off < 16; off <<= 1) fm = fmaxf(fm, __shfl_xor(fm, off, 64));
      if (l15 == 0) wmax[wc][wr * 64 + l4 * 4 + m * 16 + j] = fm;
    }
  __syncthreads();
  if (tid < 128) {
    const float fm = fmaxf(wmax[0][tid], wmax[1][tid]);
    TM[(size_t)bx * srows + by * 128 + tid] = (ushort)key16((unsigned)f2bf(fm));
  }

#pragma unroll
  for (int m = 0; m < 4; ++m)
#pragma unroll
    for (int n = 0; n < 4; ++n) {
      const int col = wc * 64 + n * 16 + l15;
      const int c8 = col >> 3, c7 = col & 7;
#pragma unroll
      for (int j = 0; j < 4; ++j) {
        const int row = wr * 64 + m * 16 + l4 * 4 + j;
        lds[row * 128 + ((c8 ^ (row & 7)) << 3) + c7] = f2bf(acc[m][n][j]);
      }
    }
  __syncthreads();
  const int orow = tid >> 4, seg = tid & 15;
#pragma unroll
  for (int p = 0; p < 8; ++p) {
    const int row = p * 16 + orow;
    const bf16x8 v = *(const bf16x8*)&lds[row * 128 + ((seg ^ (row & 7)) << 3)];
    *(bf16x8*)&C[((size_t)by * 128 + row) * NM + bx * 128 + seg * 8] = v;
  }
}

// ---------- top-32 with 128-col tile-max prefilter (R9, unchanged) ----------
#define CAP2 1024
__global__ __launch_bounds__(512) void topk_k(const ushort* __restrict__ scores,
                                              const ushort* __restrict__ tmax,
                                              int srows, int row_base,
                                              const float* __restrict__ temp,
                                              float* __restrict__ attn,
                                              int* __restrict__ idx_out) {
  const int lrow = blockIdx.x;
  const int grow = row_base + lrow;
  const int tid = threadIdx.x;
  const int lane = tid & 63, wid = tid >> 6;
  __shared__ unsigned tlb_s, M_s;
  __shared__ int nqt_s, cnt_s;
  __shared__ ushort qt[NBXT];
  __shared__ unsigned ckey[CAP2];
  __shared__ unsigned cand64[64];
  __shared__ unsigned okey[TOPK];
  __shared__ int oidx[TOPK];

  if (tid == 0) cnt_s = 0;

  if (tid < 64) {
    const unsigned k0 = tmax[(size_t)lane * srows + lrow];
    const unsigned k1 = tmax[(size_t)(lane + 64) * srows + lrow];
    const unsigned k2 = tmax[(size_t)(lane + 128) * srows + lrow];
    const unsigned k3 = tmax[(size_t)(lane + 192) * srows + lrow];
    unsigned mx = max(max(k0, k1), max(k2, k3));
#pragma unroll
    for (int off = 32; off; off >>= 1) mx = max(mx, __shfl_xor(mx, off, 64));
    unsigned lo = 0, hi = mx;
    while (lo < hi) {
      const unsigned mid = (lo + hi + 1) >> 1;
      int c = (int)(k0 >= mid) + (int)(k1 >= mid) + (int)(k2 >= mid) + (int)(k3 >= mid);
#pragma unroll
      for (int off = 32; off; off >>= 1) c += __shfl_xor(c, off, 64);
      if (c >= TOPK) lo = mid; else hi = mid - 1;
    }
    int base = 0;
    {
      const bool p = k0 >= lo;
      const unsigned long long bm = __ballot(p);
      if (p) qt[base + __popcll(bm & ((1ull << lane) - 1ull))] = (ushort)lane;
      base += __popcll(bm);
    }
    {
      const bool p = k1 >= lo;
      const unsigned long long bm = __ballot(p);
      if (p) qt[base + __popcll(bm & ((1ull << lane) - 1ull))] = (ushort)(lane + 64);
      base += __popcll(bm);
    }
    {
      const bool p = k2 >= lo;
      const unsigned long long bm = __ballot(p);
      if (p) qt[base + __popcll(bm & ((1ull << lane) - 1ull))] = (ushort)(lane + 128);
      base += __popcll(bm);
    }
    {
      const bool p = k3 >= lo;
      const unsigned long long bm = __ballot(p);
      if (p) qt[base + __popcll(bm & ((1ull << lane) - 1ull))] = (ushort)(lane + 192);
      base += __popcll(bm);
    }
    if (lane == 0) { nqt_s = base; tlb_s = lo; M_s = mx; }
  }
  __syncthreads();
  const unsigned M = M_s;
  const int nqt = nqt_s;
  unsigned t0 = tlb_s;
  unsigned tlo = t0, thi = M;

  const unsigned* rowu = (const unsigned*)(scores + (size_t)lrow * NM);
  int cnt = 0;
  for (int att = 0; att < 18; ++att) {
    for (int i = wid; i < nqt; i += 8) {
      const int tb = qt[i];
      const unsigned u = rowu[tb * 64 + lane];
      const unsigned m = (u >> 15) & 0x00010001u;
      const unsigned kk = u ^ (m * 0x7FFFu + 0x80008000u);
      const unsigned klo = kk & 0xFFFFu, khi = kk >> 16;
      const int bidx = tb * 128 + lane * 2;
      if (klo >= t0) { const int qq = atomicAdd(&cnt_s, 1); if (qq < CAP2) ckey[qq] = (klo << 16) | (unsigned)(32767 - bidx); }
      if (khi >= t0) { const int qq = atomicAdd(&cnt_s, 1); if (qq < CAP2) ckey[qq] = (khi << 16) | (unsigned)(32767 - (bidx + 1)); }
    }
    __syncthreads();
    cnt = cnt_s;
    __syncthreads();
    if ((cnt >= TOPK && cnt <= CAP2) || att == 17) break;
    if (cnt > CAP2) { tlo = t0; t0 = t0 + ((thi - t0 + 1) >> 1); }
    else { thi = t0; t0 = tlo + ((t0 - tlo) >> 1); }
    if (tid == 0) cnt_s = 0;
    __syncthreads();
  }
  const int n = min(cnt, CAP2);

  if (tid < 64) {
    unsigned lo = t0, hi = M;
    while (lo < hi) {
      const unsigned mid = (lo + hi + 1) >> 1;
      int c = 0;
      for (int i = lane; i < n; i += 64) c += (int)((ckey[i] >> 16) >= mid);
#pragma unroll
      for (int off = 32; off; off >>= 1) c += __shfl_xor(c, off, 64);
      if (c >= TOPK) lo = mid; else hi = mid - 1;
    }
    const unsigned t32 = lo;
    int c32 = 0;
    for (int i = lane; i < n; i += 64) c32 += (int)((ckey[i] >> 16) >= t32);
#pragma unroll
    for (int off = 32; off; off >>= 1) c32 += __shfl_xor(c32, off, 64);

    if (c32 <= 64) {
      cand64[lane] = 0;
      int base = 0;
      for (int r0 = 0; r0 < n; r0 += 64) {
        const int i = r0 + lane;
        const unsigned k = (i < n) ? ckey[i] : 0u;
        const bool p = (k >> 16) >= t32;
        const unsigned long long bm = __ballot(p);
        if (p) {
          const int ps = base + __popcll(bm & ((1ull << lane) - 1ull));
          if (ps < 64) cand64[ps] = k;
        }
        base += __popcll(bm);
      }
      unsigned v = cand64[lane];
#pragma unroll
      for (int k2 = 2; k2 <= 64; k2 <<= 1) {
#pragma unroll
        for (int j = k2 >> 1; j > 0; j >>= 1) {
          const unsigned o = __shfl_xor(v, j, 64);
          const bool lower = (lane & j) == 0;
          const bool descB = (lane & k2) == 0;
          const unsigned mxv = v > o ? v : o;
          const unsigned mnv = v > o ? o : v;
          v = (lower == descB) ? mxv : mnv;
        }
      }
      if (lane < TOPK) {
        okey[lane] = v >> 16;
        oidx[lane] = 32767 - (int)(v & 0x7FFFu);
      }
    } else {
      for (int k = 0; k < TOPK; ++k) {
        unsigned bk = 0;
        for (int j = lane; j < n; j += 64) bk = max(bk, ckey[j]);
#pragma unroll
        for (int off = 32; off; off >>= 1) bk = max(bk, __shfl_xor(bk, off, 64));
        if (lane == 0) {
          okey[k] = bk >> 16;
          oidx[k] = 32767 - (int)(bk & 0x7FFFu);
        }
        for (int j = lane; j < n; j += 64)
          if (ckey[j] == bk) ckey[j] = 0;
      }
    }
  }
  __syncthreads();

  if (tid < TOPK) {
    const float T = fabsf(temp[0]);
    const unsigned k0 = okey[tid];
    const unsigned u0 = (k0 & 0x8000u) ? (k0 ^ 0x8000u) : (k0 ^ 0xFFFFu);
    const unsigned km = okey[0];
    const unsigned um = (km & 0x8000u) ? (km ^ 0x8000u) : (km ^ 0xFFFFu);
    const float s = __uint_as_float(u0 << 16) * T;
    const float mx = __uint_as_float(um << 16) * T;
    const float e = __expf(s - mx);
    float sum = e;
#pragma unroll
    for (int off = 16; off; off >>= 1) sum += __shfl_xor(sum, off, 32);
    attn[(size_t)grow * TOPK + tid] = e / sum;
    idx_out[(size_t)grow * TOPK + tid] = oidx[tid];
  }
}

// ---------- bf16-V gather + residual + LayerNorm, 2 rows/block ----------
__global__ __launch_bounds__(256) void gather_ln_bf(const ushort* __restrict__ V16,
                                                    const float* __restrict__ Q,
                                                    const float* __restrict__ gamma,
                                                    const float* __restrict__ beta,
                                                    const float* __restrict__ attn,
                                                    const int* __restrict__ idx,
                                                    float* __restrict__ out) {
  const int tid = threadIdx.x;
  const int rh = tid >> 7;              // 0/1: which row of the pair
  const int t7 = tid & 127;             // lane within row
  const int row = blockIdx.x * 2 + rh;
  __shared__ float a_s[2][TOPK];
  __shared__ int i_s[2][TOPK];
  __shared__ float redS[2][2], redQ[2][2];
  if (t7 < TOPK) {
    a_s[rh][t7] = attn[(size_t)row * TOPK + t7];
    i_s[rh][t7] = idx[(size_t)row * TOPK + t7];
  }
  __syncthreads();

  const int e0 = t7 * 8;  // 8 elements per thread
  float acc[8];
#pragma unroll
  for (int u = 0; u < 8; ++u) acc[u] = 0.f;
#pragma unroll
  for (int kb = 0; kb < TOPK; kb += 8) {
    bf16x8 v[8];
#pragma unroll
    for (int u = 0; u < 8; ++u)
      v[u] = *(const bf16x8*)&V16[(size_t)i_s[rh][kb + u] * D + e0];
#pragma unroll
    for (int u = 0; u < 8; ++u) {
      const float a = a_s[rh][kb + u];
      const ushort* vu = (const ushort*)&v[u];
#pragma unroll
      for (int c = 0; c < 8; ++c) acc[c] = fmaf(a, bf2f(vu[c]), acc[c]);
    }
  }

  const float4 q0 = *(const float4*)&Q[(size_t)row * D + e0];
  const float4 q1 = *(const float4*)&Q[(size_t)row * D + e0 + 4];
  float x[8] = {acc[0] + q0.x, acc[1] + q0.y, acc[2] + q0.z, acc[3] + q0.w,
                acc[4] + q1.x, acc[5] + q1.y, acc[6] + q1.z, acc[7] + q1.w};
  float s = 0.f, ss = 0.f;
#pragma unroll
  for (int c = 0; c < 8; ++c) { s += x[c]; ss += x[c] * x[c]; }
#pragma unroll
  for (int off = 32; off; off >>= 1) {
    s += __shfl_xor(s, off, 64);
    ss += __shfl_xor(ss, off, 64);
  }
  const int w2 = (t7 >> 6);  // which of the row's 2 waves
  if ((tid & 63) == 0) { redS[rh][w2] = s; redQ[rh][w2] = ss; }
  __syncthreads();
  const float S = redS[rh][0] + redS[rh][1];
  const float SS = redQ[rh][0] + redQ[rh][1];
  const float mu = S * (1.0f / D);
  const float var = SS * (1.0f / D) - mu * mu;
  const float rstd = rsqrtf(var + 1e-5f);
  const float4 g0 = *(const float4*)&gamma[e0];
  const float4 g1 = *(const float4*)&gamma[e0 + 4];
  const float4 b0 = *(const float4*)&beta[e0];
  const float4 b1 = *(const float4*)&beta[e0 + 4];
  const float g[8] = {g0.x, g0.y, g0.z, g0.w, g1.x, g1.y, g1.z, g1.w};
  const float b[8] = {b0.x, b0.y, b0.z, b0.w, b1.x, b1.y, b1.z, b1.w};
  float4 o0, o1;
  o0.x = (x[0] - mu) * rstd * g[0] + b[0];
  o0.y = (x[1] - mu) * rstd * g[1] + b[1];
  o0.z = (x[2] - mu) * rstd * g[2] + b[2];
  o0.w = (x[3] - mu) * rstd * g[3] + b[3];
  o1.x = (x[4] - mu) * rstd * g[4] + b[4];
  o1.y = (x[5] - mu) * rstd * g[5] + b[5];
  o1.z = (x[6] - mu) * rstd * g[6] + b[6];
  o1.w = (x[7] - mu) * rstd * g[7] + b[7];
  *(float4*)&out[(size_t)row * D + e0] = o0;
  *(float4*)&out[(size_t)row * D + e0 + 4] = o1;
}

// ---------- fp32 fallback gather (used only if workspace too small for V16) ----------
__global__ __launch_bounds__(256) void gather_ln_k(const float* __restrict__ V,
                                                   const float* __restrict__ Q,
                                                   const float* __restrict__ gamma,
                                                   const float* __restrict__ beta,
                                                   const float* __restrict__ attn,
                                                   const int* __restrict__ idx,
                                                   float* __restrict__ out) {
  const int row = blockIdx.x, tid = threadIdx.x;
  __shared__ float a_s[TOPK];
  __shared__ int i_s[TOPK];
  __shared__ float redS[4], redQ[4];
  if (tid < TOPK) {
    a_s[tid] = attn[(size_t)row * TOPK + tid];
    i_s[tid] = idx[(size_t)row * TOPK + tid];
  }
  __syncthreads();
  float4 acc = {0.f, 0.f, 0.f, 0.f};
#pragma unroll
  for (int kb = 0; kb < TOPK; kb += 8) {
    float4 v[8];
#pragma unroll
    for (int u = 0; u < 8; ++u)
      v[u] = ((const float4*)(V + (size_t)i_s[kb + u] * D))[tid];
#pragma unroll
    for (int u = 0; u < 8; ++u) {
      const float a = a_s[kb + u];
      acc.x = fmaf(a, v[u].x, acc.x);
      acc.y = fmaf(a, v[u].y, acc.y);
      acc.z = fmaf(a, v[u].z, acc.z);
      acc.w = fmaf(a, v[u].w, acc.w);
    }
  }
  const float4 q = ((const float4*)(Q + (size_t)row * D))[tid];
  float4 x = {acc.x + q.x, acc.y + q.y, acc.z + q.z, acc.w + q.w};
  float s = x.x + x.y + x.z + x.w;
  float ss = x.x * x.x + x.y * x.y + x.z * x.z + x.w * x.w;
#pragma unroll
  for (int off = 32; off; off >>= 1) {
    s += __shfl_xor(s, off, 64);
    ss += __shfl_xor(ss, off, 64);
  }
  const int wid = tid >> 6, lane = tid & 63;
  if (lane == 0) { redS[wid] = s; redQ[wid] = ss; }
  __syncthreads();
  const float S = redS[0] + redS[1] + redS[2] + redS[3];
  const float SS = redQ[0] + redQ[1] + redQ[2] + redQ[3];
  const float mu = S * (1.0f / D);
  const float var = SS * (1.0f / D) - mu * mu;
  const float rstd = rsqrtf(var + 1e-5f);
  const float4 g = ((const float4*)gamma)[tid];
  const float4 b = ((const float4*)beta)[tid];
  float4 o;
  o.x = (x.x - mu) * rstd * g.x + b.x;
  o.y = (x.y - mu) * rstd * g.y + b.y;
  o.z = (x.z - mu) * rstd * g.z + b.z;
  o.w = (x.w - mu) * rstd * g.w + b.w;
  ((float4*)(out + (size_t)row * D))[tid] = o;
}

extern "C" void kernel_launch(void* const* d_in, const int* in_sizes, int n_in,
                              void* d_out, int out_size, void* d_ws, size_t ws_size,
                              hipStream_t stream) {
  const float* Q = (const float*)d_in[0];
  const float* K = (const float*)d_in[1];
  const float* V = (const float*)d_in[2];
  const float* T = (const float*)d_in[3];
  const float* G = (const float*)d_in[4];
  const float* Bt = (const float*)d_in[5];
  float* out = (float*)d_out;
  float* attn = out + (size_t)NQ * D;

  char* ws = (char*)d_ws;
  const size_t off_qn = 0;
  const size_t off_kn = off_qn + (size_t)NQ * D * 2;
  const size_t off_idx = off_kn + (size_t)NM * D * 2;
  const size_t off_tm = off_idx + (size_t)NQ * TOPK * sizeof(int);
  const size_t off_v16 = off_tm + (size_t)NBXT * 2048 * 2;
  const size_t v16_bytes = (size_t)NM * D * 2;  // 64 MB

  // can we afford the bf16 V copy + at least a 256-row score slice?
  const bool use_v16 = ws_size >= off_v16 + v16_bytes + (size_t)256 * NM * 2;
  const size_t off_sc = use_v16 ? off_v16 + v16_bytes : off_v16;

  ushort* qn = (ushort*)(ws + off_qn);
  ushort* kn = (ushort*)(ws + off_kn);
  int* idx = (int*)(ws + off_idx);
  ushort* tm = (ushort*)(ws + off_tm);
  ushort* v16 = (ushort*)(ws + off_v16);
  ushort* scores = (ushort*)(ws + off_sc);

  const size_t avail = ws_size > off_sc ? ws_size - off_sc : 0;
  int slice = 2048;
  while (slice > 256 && (size_t)slice * NM * 2ull > avail) slice >>= 1;

  norm_cast_k<<<NQ, 256, 0, stream>>>(Q, qn);
  norm_cast_k<<<NM, 256, 0, stream>>>(K, kn);
  if (use_v16) cast_v_k<<<NM, 256, 0, stream>>>(V, v16);

  const int nbx = NM / 128;
  for (int s0 = 0; s0 < NQ; s0 += slice) {
    const int nby = slice / 128;
    gemm128<<<nbx * nby, 256, 0, stream>>>(qn + (size_t)s0 * D, kn, scores, tm, nby, slice);
    topk_k<<<slice, 512, 0, stream>>>(scores, tm, slice, s0, T, attn, idx);
  }
  if (use_v16)
    gather_ln_bf<<<NQ / 2, 256, 0, stream>>>(v16, Q, G, Bt, attn, idx, out);
  else
    gather_ln_k<<<NQ, 256, 0, stream>>>(V, Q, G, Bt, attn, idx, out);
}